// Round 2
// baseline (1395.504 us; speedup 1.0000x reference)
//
#include <hip/hip_runtime.h>
#include <hip/hip_bf16.h>
#include <hip/hip_fp16.h>
#include <math.h>

#define N_NODES 50000
#define NP      50048          // padded node count (multiple of 64)
#define SEQ     16
#define FIN     64
#define HID     128
#define NEDGE   1600000
#define NB_SCAN 196            // ceil(50000/256)
#define AGG_CAP 96

typedef __attribute__((ext_vector_type(8))) short short8;   // 8 bf16 = 4 VGPRs
typedef __attribute__((ext_vector_type(4))) float f32x4;

__device__ __forceinline__ float lrelu02(float v) { return v > 0.f ? v : 0.2f * v; }
__device__ __forceinline__ float frcp(float v) { return __builtin_amdgcn_rcpf(v); }
__device__ __forceinline__ float ex2(float v) { return __builtin_amdgcn_exp2f(v); }
__device__ __forceinline__ float sigmoidf_(float v) { return frcp(1.f + __expf(-v)); }
__device__ __forceinline__ float eluf_(float v) { return v > 0.f ? v : (__expf(v) - 1.f); }

// packed fp32x2 -> bf16x2 (v_cvt_pk_bf16_f32 on gfx950), RNE
__device__ __forceinline__ unsigned bfpk(float lo, float hi) {
    union { __hip_bfloat162 h; unsigned u; } c;
    c.h = __float22bfloat162_rn(make_float2(lo, hi));
    return c.u;
}
// packed fp32x2 -> fp16x2
__device__ __forceinline__ unsigned hfpk(float lo, float hi) {
    union { __half2 h; unsigned u; } c;
    c.h = __float22half2_rn(make_float2(lo, hi));
    return c.u;
}
__device__ __forceinline__ float2 h2f2(unsigned u) {
    union { unsigned u; __half2 h; } c;
    c.u = u;
    return __half22float2(c.h);
}
// pack 8 floats (scaled) to bf16x8
__device__ __forceinline__ short8 pack8s(float4 a, float4 b, float s) {
    union { short8 sv; unsigned u[4]; } r;
    r.u[0] = bfpk(a.x * s, a.y * s); r.u[1] = bfpk(a.z * s, a.w * s);
    r.u[2] = bfpk(b.x * s, b.y * s); r.u[3] = bfpk(b.z * s, b.w * s);
    return r.sv;
}

// raw barrier: LDS-visibility only. __syncthreads() would also drain
// vmcnt(0), killing the cross-phase x prefetch (guide: compiler emits
// "s_waitcnt vmcnt(0) lgkmcnt(0)" before s_barrier). The "memory"
// clobber pins LDS ops and the prefetch load inside their phase.
#define BAR() do { asm volatile("s_waitcnt lgkmcnt(0)" ::: "memory"); \
                   __builtin_amdgcn_s_barrier(); } while (0)

// ---------------------------------------------------------------------------
// Fused GRU: one block = 64 nodes = two 32-node groups (A/B), 512 threads.
// Two phases per timestep (one per group), one RAW barrier per phase.
//  - frag ds_reads issue at phase TOP (sources finalized >=1 barrier ago);
//  - prev phase's h crosses the barrier packed in registers, LDS-written
//    early next phase inside the frag-read shadow;
//  - x(t+1) global load issued mid-phase, consumed next phase TOP; with the
//    raw barrier (no vmcnt drain) the load now truly spans a full phase.
// Trans-unit diet (quarter-rate exp/rcp was a 125 us floor):
//  - weights/biases prefolded by log2e (r,z) / 2*log2e (n) -> v_exp_f32
//    (2^x) used directly, no ln2 multiplies;
//  - one rcp serves both sigmoids: 1/dr = rcp(dr*dz)*dz; tanh rcps paired
//    across elements the same way. 6 trans/el -> 4.5 (floor ~94 us).
//    Caps (60/120 in exp2 domain) keep products finite; saturated cases
//    recover exact limits (sigma->0, tanh->1).
// ---------------------------------------------------------------------------
__global__ __launch_bounds__(512, 4) void gru_fused(
    const float* __restrict__ x,     // [N][16][64]
    const float* __restrict__ w_ih,  // [384][64]
    const float* __restrict__ w_hh,  // [384][128]
    const float* __restrict__ b_ih,  // [384]
    const float* __restrict__ b_hh,  // [384]
    float* __restrict__ hout)        // [NP][128]
{
    // [group][buf][node][ch], 16B-aligned rows (272B / 144B strides)
    __shared__ __align__(16) short hA[2][2][32][136];
    __shared__ __align__(16) short xB[2][2][32][72];

    const int tid  = threadIdx.x;
    const int wave = tid >> 6;
    const int lane = tid & 63;
    const int q    = lane >> 4;      // quad 0..3
    const int rl   = lane & 15;
    const int n0   = blockIdx.x * 64;
    const int ch   = wave * 16 + rl; // channel within gate

    // ---- resident weight B-fragments (bf16), exp2-prefolded scales ----
    const float S1 = 1.44269504088896341f;   // log2(e)
    const float S2 = 2.88539008177792682f;   // 2*log2(e)
    short8 whhf[3][4];   // [gate][kc] K=128
    short8 wihf[3][2];   // [gate][kc] K=64
#pragma unroll
    for (int g = 0; g < 3; g++) {
        const float gs = (g == 2) ? S2 : S1;
        int row = g * 128 + ch;
#pragma unroll
        for (int kc = 0; kc < 4; kc++) {
            const float* p = w_hh + row * HID + kc * 32 + q * 8;
            whhf[g][kc] = pack8s(*(const float4*)p, *(const float4*)(p + 4), gs);
        }
#pragma unroll
        for (int kc = 0; kc < 2; kc++) {
            const float* p = w_ih + row * FIN + kc * 32 + q * 8;
            wihf[g][kc] = pack8s(*(const float4*)p, *(const float4*)(p + 4), gs);
        }
    }

    // per-lane biases (prefolded)
    const float br  = (b_ih[ch] + b_hh[ch]) * S1;
    const float bz  = (b_ih[128 + ch] + b_hh[128 + ch]) * S1;
    const float bin = b_ih[256 + ch] * S2;
    const float bhn = b_hh[256 + ch] * S2;

    // staging assignment: thread owns 4 consecutive floats of a 32x64 tile
    const int sn = tid >> 4;          // node-in-group 0..31
    const int sk = (tid & 15) * 4;    // k 0..60
    int g0n = n0 + sn;      if (g0n > N_NODES - 1) g0n = N_NODES - 1;
    int g1n = n0 + 32 + sn; if (g1n > N_NODES - 1) g1n = N_NODES - 1;
    const float* xs0 = x + (size_t)g0n * SEQ * FIN + sk;
    const float* xs1 = x + (size_t)g1n * SEQ * FIN + sk;

    // h state: lane holds (node-in-group = mt*16 + q*4 + r, this ch)
    float hreg[2][2][4];   // [group][mt][r]
#pragma unroll
    for (int g = 0; g < 2; g++)
#pragma unroll
        for (int mt = 0; mt < 2; mt++)
#pragma unroll
            for (int r = 0; r < 4; r++) hreg[g][mt][r] = 0.f;

    // cross-phase register carry: packed h of previous phase + staged x
    unsigned hp01[2], hp23[2];
    float4 xhold;

    // prologue: stage x(g0,t=0) into LDS; preload x(g1,t=0) into xhold
    {
        float4 v = *(const float4*)(xs0);
        int2 pv;
        pv.x = (int)bfpk(v.x, v.y);
        pv.y = (int)bfpk(v.z, v.w);
        *(int2*)&xB[0][0][sn][sk] = pv;
    }
    xhold = *(const float4*)(xs1);
    BAR();

// One phase: group G, timestep t.
//   DO_HW/HWB : write prev-phase h (group G^1) into hA[G^1][HWB]
//   DO_XW/XWB : write xhold (x for group G^1) into xB[G^1][XWB]
//   DO_XL/XLP : issue global load of next x for THIS group into xhold
#define GRU_PHASE(G, DO_HW, HWB, DO_XW, XWB, DO_XL, XLP)                          \
    {                                                                             \
        const int rb = (t - 1) & 1;                                               \
        short8 xf[2][2], hf[2][4];                                                \
        _Pragma("unroll")                                                         \
        for (int mt = 0; mt < 2; mt++)                                            \
            _Pragma("unroll")                                                     \
            for (int kc = 0; kc < 2; kc++)                                        \
                xf[mt][kc] = *(const short8*)&xB[G][t & 1][mt * 16 + rl][kc * 32 + q * 8]; \
        if (t > 0) {                                                              \
            _Pragma("unroll")                                                     \
            for (int mt = 0; mt < 2; mt++)                                        \
                _Pragma("unroll")                                                 \
                for (int kc = 0; kc < 4; kc++)                                    \
                    hf[mt][kc] = *(const short8*)&hA[G][rb][mt * 16 + rl][kc * 32 + q * 8]; \
        }                                                                         \
        /* deferred writes: hidden under the frag-read latency */                 \
        if (DO_HW) {                                                              \
            _Pragma("unroll")                                                     \
            for (int mt = 0; mt < 2; mt++) {                                      \
                const int nb = mt * 16 + q * 4;                                   \
                hA[G ^ 1][HWB][nb + 0][ch] = (short)(hp01[mt] & 0xFFFF);          \
                hA[G ^ 1][HWB][nb + 1][ch] = (short)(hp01[mt] >> 16);             \
                hA[G ^ 1][HWB][nb + 2][ch] = (short)(hp23[mt] & 0xFFFF);          \
                hA[G ^ 1][HWB][nb + 3][ch] = (short)(hp23[mt] >> 16);             \
            }                                                                     \
        }                                                                         \
        if (DO_XW) {                                                              \
            int2 pv;                                                              \
            pv.x = (int)bfpk(xhold.x, xhold.y);                                   \
            pv.y = (int)bfpk(xhold.z, xhold.w);                                   \
            *(int2*)&xB[G ^ 1][XWB][sn][sk] = pv;                                 \
        }                                                                         \
        if (DO_XL) xhold = *(const float4*)(XLP);   /* consumed next phase */     \
        f32x4 accr[2], accz[2], accin[2], acchn[2];                               \
        _Pragma("unroll")                                                         \
        for (int mt = 0; mt < 2; mt++) {                                          \
            accr[mt] = (f32x4)0.f; accz[mt] = (f32x4)0.f;                         \
            accin[mt] = (f32x4)0.f; acchn[mt] = (f32x4)0.f;                       \
            _Pragma("unroll")                                                     \
            for (int kc = 0; kc < 2; kc++) {                                      \
                accr[mt]  = __builtin_amdgcn_mfma_f32_16x16x32_bf16(xf[mt][kc], wihf[0][kc], accr[mt], 0, 0, 0);  \
                accz[mt]  = __builtin_amdgcn_mfma_f32_16x16x32_bf16(xf[mt][kc], wihf[1][kc], accz[mt], 0, 0, 0);  \
                accin[mt] = __builtin_amdgcn_mfma_f32_16x16x32_bf16(xf[mt][kc], wihf[2][kc], accin[mt], 0, 0, 0); \
            }                                                                     \
            if (t > 0) {                                                          \
                _Pragma("unroll")                                                 \
                for (int kc = 0; kc < 4; kc++) {                                  \
                    accr[mt]  = __builtin_amdgcn_mfma_f32_16x16x32_bf16(hf[mt][kc], whhf[0][kc], accr[mt], 0, 0, 0);  \
                    accz[mt]  = __builtin_amdgcn_mfma_f32_16x16x32_bf16(hf[mt][kc], whhf[1][kc], accz[mt], 0, 0, 0);  \
                    acchn[mt] = __builtin_amdgcn_mfma_f32_16x16x32_bf16(hf[mt][kc], whhf[2][kc], acchn[mt], 0, 0, 0); \
                }                                                                 \
            }                                                                     \
        }                                                                         \
        _Pragma("unroll")                                                         \
        for (int mt = 0; mt < 2; mt++) {                                          \
            float rg[4], zg[4], et[4], hv[4];                                     \
            _Pragma("unroll")                                                     \
            for (int r = 0; r < 4; r++) {                                         \
                float er = ex2(fminf(-(accr[mt][r] + br), 60.f));                 \
                float ez = ex2(fminf(-(accz[mt][r] + bz), 60.f));                 \
                float dr = er + 1.f, dz = ez + 1.f;                               \
                float ip = frcp(dr * dz);                                         \
                rg[r] = dz * ip; zg[r] = dr * ip;                                 \
                float ap = accin[mt][r] + bin + rg[r] * (acchn[mt][r] + bhn);     \
                et[r] = ex2(fminf(ap, 120.f));                                    \
            }                                                                     \
            _Pragma("unroll")                                                     \
            for (int pr = 0; pr < 2; pr++) {                                      \
                float d0 = et[2 * pr] + 1.f, d1 = et[2 * pr + 1] + 1.f;           \
                float ipt = frcp(d0 * d1);                                        \
                float nn0 = 1.f - 2.f * (ipt * d1);                               \
                float nn1 = 1.f - 2.f * (ipt * d0);                               \
                float h0 = zg[2 * pr]     * (hreg[G][mt][2 * pr]     - nn0) + nn0; \
                float h1 = zg[2 * pr + 1] * (hreg[G][mt][2 * pr + 1] - nn1) + nn1; \
                hreg[G][mt][2 * pr] = h0; hreg[G][mt][2 * pr + 1] = h1;           \
                hv[2 * pr] = h0; hv[2 * pr + 1] = h1;                             \
            }                                                                     \
            hp01[mt] = bfpk(hv[0], hv[1]);                                        \
            hp23[mt] = bfpk(hv[2], hv[3]);                                        \
        }                                                                         \
        BAR();                                                                    \
    }

    for (int t = 0; t < SEQ; t++) {
        // phase (g=0,t): write h(g1,t-1)->hA[1][(t-1)&1]; write x(g1,t)->xB[1][t&1]
        GRU_PHASE(0, (t > 0), ((t - 1) & 1), 1, (t & 1),
                  (t + 1 < SEQ), (xs0 + (t + 1) * FIN))
        // phase (g=1,t): write h(g0,t)->hA[0][t&1]; write x(g0,t+1)->xB[0][(t+1)&1]
        GRU_PHASE(1, 1, (t & 1), (t + 1 < SEQ), ((t + 1) & 1),
                  (t + 1 < SEQ), (xs1 + (t + 1) * FIN))
    }
#undef GRU_PHASE

    // final h to global (fp32), straight from registers
#pragma unroll
    for (int g = 0; g < 2; g++)
#pragma unroll
        for (int mt = 0; mt < 2; mt++)
#pragma unroll
            for (int r = 0; r < 4; r++)
                hout[(size_t)(n0 + g * 32 + mt * 16 + q * 4 + r) * HID + ch] = hreg[g][mt][r];
}

// ---------------------------------------------------------------------------
// weight prep for GAT projections: w[g][k] -> [k][g]
// ---------------------------------------------------------------------------
__global__ void prep_weights(const float* __restrict__ g1w, const float* __restrict__ g2w,
                             float* __restrict__ g1T, float* __restrict__ g2T)
{
    int i = blockIdx.x * 256 + threadIdx.x;
    if (i < 128 * 128) {
        int k = i >> 7, g = i & 127;
        g1T[i] = g1w[g * 128 + k];
        g2T[i] = g2w[g * 128 + k];
    }
}

// ---------------------------------------------------------------------------
// CSR build
// ---------------------------------------------------------------------------
__global__ void count_edges(const int* __restrict__ dst, int* __restrict__ deg, int e)
{
    int i = blockIdx.x * 256 + threadIdx.x;
    if (i < e) atomicAdd(&deg[dst[i]], 1);
}

__device__ __forceinline__ int block_scan_inc(int v)
{
    int tid = threadIdx.x, lane = tid & 63, w = tid >> 6;
#pragma unroll
    for (int off = 1; off < 64; off <<= 1) {
        int tmp = __shfl_up(v, off, 64);
        if (lane >= off) v += tmp;
    }
    __shared__ int wsum[4];
    if (lane == 63) wsum[w] = v;
    __syncthreads();
    int add = 0;
    for (int i = 0; i < w; i++) add += wsum[i];
    return v + add;
}

__global__ void scan_block_sums(const int* __restrict__ deg, int* __restrict__ bsum, int n)
{
    int i = blockIdx.x * 256 + threadIdx.x;
    int v = (i < n) ? deg[i] : 0;
#pragma unroll
    for (int off = 32; off >= 1; off >>= 1) v += __shfl_xor(v, off, 64);
    __shared__ int ws[4];
    if ((threadIdx.x & 63) == 0) ws[threadIdx.x >> 6] = v;
    __syncthreads();
    if (threadIdx.x == 0) bsum[blockIdx.x] = ws[0] + ws[1] + ws[2] + ws[3];
}

__global__ void scan_bsum(int* __restrict__ bsum, int nb)
{
    int tid = threadIdx.x;
    int v = (tid < nb) ? bsum[tid] : 0;
    v = block_scan_inc(v);
    if (tid < nb) bsum[tid] = v;
}

__global__ void scan_final(const int* __restrict__ deg, const int* __restrict__ bsum,
                           int* __restrict__ rp, int n)
{
    int i = blockIdx.x * 256 + threadIdx.x;
    int v = (i < n) ? deg[i] : 0;
    int s = block_scan_inc(v);
    int add = (blockIdx.x > 0) ? bsum[blockIdx.x - 1] : 0;
    if (i < n) rp[i + 1] = s + add;
    if (i == 0) rp[0] = 0;
}

__global__ void fill_edges(const int* __restrict__ src, const int* __restrict__ dst,
                           const int* __restrict__ rp, int* __restrict__ cur,
                           int* __restrict__ col, int e)
{
    int i = blockIdx.x * 256 + threadIdx.x;
    if (i < e) {
        int d = dst[i];
        int pos = atomicAdd(&cur[d], 1);
        col[rp[d] + pos] = src[i];
    }
}

// ---------------------------------------------------------------------------
// GAT projection + attention coefficients, fused.
// hp = x @ wT (fp32 accum); writes fp16-packed feature rows (hph) and
// per-(node,head) a_src/a_dst dots (as_, ad_). 32 nodes/block.
// ---------------------------------------------------------------------------
__global__ __launch_bounds__(256) void proj_attn(
    const float* __restrict__ x, const float* __restrict__ wT,
    const float* __restrict__ a_src, const float* __restrict__ a_dst,
    unsigned* __restrict__ hph, float* __restrict__ as_, float* __restrict__ ad_)
{
    __shared__ float xt[32][33];
    __shared__ float wt[32][128];
    __shared__ float ot[32][132];     // 132: 16B-aligned rows for float4 reads
    const int tid = threadIdx.x;
    const int tx = tid & 7;       // 8 node groups of 4
    const int ty = tid >> 3;      // 32 out groups of 4
    const int n0 = blockIdx.x * 32;
    float acc[4][4];
#pragma unroll
    for (int i = 0; i < 4; i++)
#pragma unroll
        for (int j = 0; j < 4; j++) acc[i][j] = 0.f;

    for (int k0 = 0; k0 < 128; k0 += 32) {
        __syncthreads();
#pragma unroll
        for (int i = 0; i < 4; i++) {
            int flat = tid + i * 256;
            int n = flat >> 5, k = flat & 31;
            xt[n][k] = x[(n0 + n) * HID + k0 + k];
        }
#pragma unroll
        for (int i = 0; i < 16; i++) {
            int flat = tid + i * 256;
            int kk = flat >> 7, g = flat & 127;
            wt[kk][g] = wT[(k0 + kk) * HID + g];
        }
        __syncthreads();
#pragma unroll 8
        for (int kk = 0; kk < 32; kk++) {
            float xv[4];
#pragma unroll
            for (int i = 0; i < 4; i++) xv[i] = xt[tx * 4 + i][kk];
            float4 wv = *(const float4*)&wt[kk][ty * 4];
#pragma unroll
            for (int i = 0; i < 4; i++) {
                acc[i][0] = fmaf(xv[i], wv.x, acc[i][0]);
                acc[i][1] = fmaf(xv[i], wv.y, acc[i][1]);
                acc[i][2] = fmaf(xv[i], wv.z, acc[i][2]);
                acc[i][3] = fmaf(xv[i], wv.w, acc[i][3]);
            }
        }
    }
    // epilogue: fp16-packed store + LDS tile for attention dots
#pragma unroll
    for (int i = 0; i < 4; i++) {
        int node = tx * 4 + i;
        ot[node][ty * 4 + 0] = acc[i][0];
        ot[node][ty * 4 + 1] = acc[i][1];
        ot[node][ty * 4 + 2] = acc[i][2];
        ot[node][ty * 4 + 3] = acc[i][3];
        uint2 pv;
        pv.x = hfpk(acc[i][0], acc[i][1]);
        pv.y = hfpk(acc[i][2], acc[i][3]);
        *(uint2*)&hph[(size_t)(n0 + node) * 64 + ty * 2] = pv;
    }
    __syncthreads();
    if (tid < 128) {
        int node = tid >> 2, head = tid & 3;
        const float* ar = a_src + head * 32;
        const float* br = a_dst + head * 32;
        float s = 0.f, d = 0.f;
#pragma unroll
        for (int j = 0; j < 32; j += 4) {
            float4 hv = *(const float4*)&ot[node][head * 32 + j];
            float4 av = *(const float4*)&ar[j];
            float4 bv = *(const float4*)&br[j];
            s += hv.x * av.x + hv.y * av.y + hv.z * av.z + hv.w * av.w;
            d += hv.x * bv.x + hv.y * bv.y + hv.z * bv.z + hv.w * bv.w;
        }
        as_[(n0 + node) * 4 + head] = s;
        ad_[(n0 + node) * 4 + head] = d;
    }
}

// ---------------------------------------------------------------------------
// GAT aggregation: one wave per dst node, CSR + implicit self-loop.
// Features gathered as fp16 pairs: lane owns channels (2*lane, 2*lane+1),
// one dword per edge per lane, coalesced. No max-pass (logits O(5), fp32 exp
// safe; shift is a mathematical no-op). CLF: classifier fused.
// ---------------------------------------------------------------------------
template <bool CLF>
__global__ __launch_bounds__(256) void gat_agg(
    const unsigned* __restrict__ hph, const float* __restrict__ as_,
    const float* __restrict__ ad_, const int* __restrict__ rp,
    const int* __restrict__ col, const float* __restrict__ bias,
    float* __restrict__ out, const float* __restrict__ cw,
    const float* __restrict__ cb, int n_nodes)
{
    __shared__ float exl[4][AGG_CAP][4];
    const int widx = threadIdx.x >> 6;
    const int lane = threadIdx.x & 63;
    const int n = blockIdx.x * 4 + widx;
    if (n >= n_nodes) return;

    const int e0 = rp[n], e1 = rp[n + 1];
    const int deg = e1 - e0;
    float4 adv = *(const float4*)&ad_[n * 4];
    float4 asn = *(const float4*)&as_[n * 4];
    // self-loop exp
    float xs0 = __expf(lrelu02(asn.x + adv.x)), xs1 = __expf(lrelu02(asn.y + adv.y));
    float xs2 = __expf(lrelu02(asn.z + adv.z)), xs3 = __expf(lrelu02(asn.w + adv.w));

    // phase A: exp per edge (lane-strided), cache in LDS, accumulate denoms
    float d0 = 0.f, d1 = 0.f, d2 = 0.f, d3 = 0.f;
    for (int e = e0 + lane; e < e1; e += 64) {
        int s = col[e];
        float4 a = *(const float4*)&as_[s * 4];
        float x0 = __expf(lrelu02(a.x + adv.x));
        float x1 = __expf(lrelu02(a.y + adv.y));
        float x2 = __expf(lrelu02(a.z + adv.z));
        float x3 = __expf(lrelu02(a.w + adv.w));
        int idx = e - e0;
        if (idx < AGG_CAP) {
            exl[widx][idx][0] = x0; exl[widx][idx][1] = x1;
            exl[widx][idx][2] = x2; exl[widx][idx][3] = x3;
        }
        d0 += x0; d1 += x1; d2 += x2; d3 += x3;
    }
#pragma unroll
    for (int off = 32; off >= 1; off >>= 1) {
        d0 += __shfl_xor(d0, off, 64);
        d1 += __shfl_xor(d1, off, 64);
        d2 += __shfl_xor(d2, off, 64);
        d3 += __shfl_xor(d3, off, 64);
    }
    d0 += xs0; d1 += xs1; d2 += xs2; d3 += xs3;
    float i0 = frcp(d0 + 1e-16f), i1 = frcp(d1 + 1e-16f);
    float i2 = frcp(d2 + 1e-16f), i3 = frcp(d3 + 1e-16f);

    // phase B: lane owns channel pair (2*lane, 2*lane+1); head = lane>>4
    const int head = lane >> 4;
    float invh = (head == 0) ? i0 : (head == 1) ? i1 : (head == 2) ? i2 : i3;
    float exsh = (head == 0) ? xs0 : (head == 1) ? xs1 : (head == 2) ? xs2 : xs3;
    float adh  = (head == 0) ? adv.x : (head == 1) ? adv.y : (head == 2) ? adv.z : adv.w;

    float2 sv = h2f2(hph[(size_t)n * 64 + lane]);
    float acc0 = exsh * sv.x;
    float acc1 = exsh * sv.y;

    if (deg <= AGG_CAP) {
        int e = e0;
        for (; e + 4 <= e1; e += 4) {
            int s_[4]; float w_[4]; unsigned u_[4];
#pragma unroll
            for (int u = 0; u < 4; u++) {
                s_[u] = col[e + u];
                w_[u] = exl[widx][e + u - e0][head];
            }
#pragma unroll
            for (int u = 0; u < 4; u++)
                u_[u] = hph[(size_t)s_[u] * 64 + lane];
#pragma unroll
            for (int u = 0; u < 4; u++) {
                float2 f = h2f2(u_[u]);
                acc0 = fmaf(w_[u], f.x, acc0);
                acc1 = fmaf(w_[u], f.y, acc1);
            }
        }
        for (; e < e1; e++) {
            int s = col[e];
            float w = exl[widx][e - e0][head];
            float2 f = h2f2(hph[(size_t)s * 64 + lane]);
            acc0 = fmaf(w, f.x, acc0);
            acc1 = fmaf(w, f.y, acc1);
        }
    } else {
        for (int e = e0; e < e1; e++) {
            int s = col[e];
            int idx = e - e0;
            float w;
            if (idx < AGG_CAP) w = exl[widx][idx][head];
            else               w = __expf(lrelu02(as_[s * 4 + head] + adh));
            float2 f = h2f2(hph[(size_t)s * 64 + lane]);
            acc0 = fmaf(w, f.x, acc0);
            acc1 = fmaf(w, f.y, acc1);
        }
    }

    float2 b2 = *(const float2*)&bias[2 * lane];
    float o0 = eluf_(acc0 * invh + b2.x);
    float o1 = eluf_(acc1 * invh + b2.y);
    if (CLF) {
        float2 cwv = *(const float2*)&cw[2 * lane];
        float v = o0 * cwv.x + o1 * cwv.y;
#pragma unroll
        for (int off = 32; off >= 1; off >>= 1) v += __shfl_xor(v, off, 64);
        if (lane == 0) out[n] = sigmoidf_(v + cb[0]);
    } else {
        *(float2*)&out[(size_t)n * HID + 2 * lane] = make_float2(o0, o1);
    }
}

// ---------------------------------------------------------------------------
extern "C" void kernel_launch(void* const* d_in, const int* in_sizes, int n_in,
                              void* d_out, int out_size, void* d_ws, size_t ws_size,
                              hipStream_t stream)
{
    const float* x     = (const float*)d_in[0];
    const int*   ei    = (const int*)d_in[1];
    const float* w_ih  = (const float*)d_in[2];
    const float* w_hh  = (const float*)d_in[3];
    const float* b_ih  = (const float*)d_in[4];
    const float* b_hh  = (const float*)d_in[5];
    const float* g1w   = (const float*)d_in[6];
    const float* g1as  = (const float*)d_in[7];
    const float* g1ad  = (const float*)d_in[8];
    const float* g1b   = (const float*)d_in[9];
    const float* g2w   = (const float*)d_in[10];
    const float* g2as  = (const float*)d_in[11];
    const float* g2ad  = (const float*)d_in[12];
    const float* g2b   = (const float*)d_in[13];
    const float* cw    = (const float*)d_in[14];
    const float* cb    = (const float*)d_in[15];
    float* out = (float*)d_out;

    char* wsb = (char*)d_ws;
    size_t off = 0;
    auto alc = [&](size_t bytes) { size_t o = off; off += (bytes + 255) & ~(size_t)255; return o; };

    float*    bufA = (float*)(wsb + alc((size_t)NP * HID * 4));      // GRU h
    float*    bufC = (float*)(wsb + alc((size_t)NP * HID * 4));      // layer-1 out
    unsigned* hph  = (unsigned*)(wsb + alc((size_t)NP * 64 * 4));    // fp16-packed features
    float*    as_  = (float*)(wsb + alc((size_t)NP * 4 * 4));
    float*    ad_  = (float*)(wsb + alc((size_t)NP * 4 * 4));
    float*    g1T  = (float*)(wsb + alc((size_t)128 * 128 * 4));
    float*    g2T  = (float*)(wsb + alc((size_t)128 * 128 * 4));
    int*      rp   = (int*)(wsb + alc((size_t)(N_NODES + 1) * 4));
    int*      deg  = (int*)(wsb + alc((size_t)N_NODES * 4));
    int*      cur  = (int*)(wsb + alc((size_t)N_NODES * 4));
    int*      col  = (int*)(wsb + alc((size_t)NEDGE * 4));
    int*      bsum = (int*)(wsb + alc((size_t)256 * 4));

    const int* src = ei;
    const int* dst = ei + NEDGE;

    hipMemsetAsync(deg, 0, (size_t)N_NODES * 4, stream);
    hipMemsetAsync(cur, 0, (size_t)N_NODES * 4, stream);

    prep_weights<<<64, 256, 0, stream>>>(g1w, g2w, g1T, g2T);

    // CSR build (reused by both GAT layers)
    count_edges<<<NEDGE / 256, 256, 0, stream>>>(dst, deg, NEDGE);
    scan_block_sums<<<NB_SCAN, 256, 0, stream>>>(deg, bsum, N_NODES);
    scan_bsum<<<1, 256, 0, stream>>>(bsum, NB_SCAN);
    scan_final<<<NB_SCAN, 256, 0, stream>>>(deg, bsum, rp, N_NODES);
    fill_edges<<<NEDGE / 256, 256, 0, stream>>>(src, dst, rp, cur, col, NEDGE);

    // fused GRU (all 16 steps), bf16 MFMA, A/B pipelined, h -> bufA
    gru_fused<<<NP / 64, 512, 0, stream>>>(x, w_ih, w_hh, b_ih, b_hh, bufA);

    // GAT layer 1: bufA -> hph/as_/ad_ (proj+attn) -> bufC (agg+elu)
    proj_attn<<<NP / 32, 256, 0, stream>>>(bufA, g1T, g1as, g1ad, hph, as_, ad_);
    gat_agg<false><<<(N_NODES + 3) / 4, 256, 0, stream>>>(hph, as_, ad_, rp, col, g1b, bufC,
                                                          nullptr, nullptr, N_NODES);

    // GAT layer 2: bufC -> hph/as_/ad_; agg fused with classifier -> out
    proj_attn<<<NP / 32, 256, 0, stream>>>(bufC, g2T, g2as, g2ad, hph, as_, ad_);
    gat_agg<true><<<(N_NODES + 3) / 4, 256, 0, stream>>>(hph, as_, ad_, rp, col, g2b, out,
                                                         cw, cb, N_NODES);
}

// Round 3
// 840.779 us; speedup vs baseline: 1.6598x; 1.6598x over previous
//
#include <hip/hip_runtime.h>
#include <hip/hip_bf16.h>
#include <hip/hip_fp16.h>
#include <math.h>

#define N_NODES 50000
#define NP      50048          // padded node count (multiple of 64)
#define SEQ     16
#define FIN     64
#define HID     128
#define NEDGE   1600000
#define NB_SCAN 196            // ceil(50000/256)
#define AGG_CAP 96

typedef __attribute__((ext_vector_type(8))) short short8;   // 8 bf16 = 4 VGPRs
typedef __attribute__((ext_vector_type(4))) float f32x4;

__device__ __forceinline__ float lrelu02(float v) { return v > 0.f ? v : 0.2f * v; }
__device__ __forceinline__ float frcp(float v) { return __builtin_amdgcn_rcpf(v); }
__device__ __forceinline__ float ex2(float v) { return __builtin_amdgcn_exp2f(v); }
__device__ __forceinline__ float sigmoidf_(float v) { return frcp(1.f + __expf(-v)); }
__device__ __forceinline__ float eluf_(float v) { return v > 0.f ? v : (__expf(v) - 1.f); }

// packed fp32x2 -> bf16x2 (v_cvt_pk_bf16_f32 on gfx950), RNE
__device__ __forceinline__ unsigned bfpk(float lo, float hi) {
    union { __hip_bfloat162 h; unsigned u; } c;
    c.h = __float22bfloat162_rn(make_float2(lo, hi));
    return c.u;
}
// packed fp32x2 -> fp16x2
__device__ __forceinline__ unsigned hfpk(float lo, float hi) {
    union { __half2 h; unsigned u; } c;
    c.h = __float22half2_rn(make_float2(lo, hi));
    return c.u;
}
__device__ __forceinline__ float2 h2f2(unsigned u) {
    union { unsigned u; __half2 h; } c;
    c.u = u;
    return __half22float2(c.h);
}
// pack 8 floats (scaled) to bf16x8
__device__ __forceinline__ short8 pack8s(float4 a, float4 b, float s) {
    union { short8 sv; unsigned u[4]; } r;
    r.u[0] = bfpk(a.x * s, a.y * s); r.u[1] = bfpk(a.z * s, a.w * s);
    r.u[2] = bfpk(b.x * s, b.y * s); r.u[3] = bfpk(b.z * s, b.w * s);
    return r.sv;
}

// raw barrier: LDS-visibility only. __syncthreads() would also drain
// vmcnt(0), killing the cross-phase x prefetch (guide: compiler emits
// "s_waitcnt vmcnt(0) lgkmcnt(0)" before s_barrier). The "memory"
// clobber pins LDS ops and the prefetch load inside their phase.
#define BAR() do { asm volatile("s_waitcnt lgkmcnt(0)" ::: "memory"); \
                   __builtin_amdgcn_s_barrier(); } while (0)

// ---------------------------------------------------------------------------
// Fused GRU: one block = 64 nodes = two 32-node groups (A/B), 512 threads.
// Two phases per timestep (one per group), one RAW barrier per phase.
//  - frag ds_reads issue at phase TOP (sources finalized >=1 barrier ago);
//  - prev phase's h crosses the barrier packed in registers, LDS-written
//    early next phase inside the frag-read shadow;
//  - x(t+1) global load issued mid-phase, consumed next phase TOP; with the
//    raw barrier (no vmcnt drain) the load truly spans a full phase.
// Trans-unit diet (quarter-rate exp/rcp was a 125 us floor):
//  - weights/biases prefolded by log2e (r,z) / 2*log2e (n) -> v_exp_f32
//    (2^x) used directly, no ln2 multiplies;
//  - one rcp serves both sigmoids: 1/dr = rcp(dr*dz)*dz; tanh rcps paired
//    across elements the same way. 6 trans/el -> 4.5 (floor ~94 us).
// __launch_bounds__(512,2): R2's (512,4) capped VGPR at 128 -> massive
// scratch spills (FETCH 105MB->1.5GB, WRITE 25->894MB). 2 waves/EU gives
// the allocator a 256-VGPR budget; body needs ~150, no spill.
// ---------------------------------------------------------------------------
__global__ __launch_bounds__(512, 2) void gru_fused(
    const float* __restrict__ x,     // [N][16][64]
    const float* __restrict__ w_ih,  // [384][64]
    const float* __restrict__ w_hh,  // [384][128]
    const float* __restrict__ b_ih,  // [384]
    const float* __restrict__ b_hh,  // [384]
    float* __restrict__ hout)        // [NP][128]
{
    // [group][buf][node][ch], 16B-aligned rows (272B / 144B strides)
    __shared__ __align__(16) short hA[2][2][32][136];
    __shared__ __align__(16) short xB[2][2][32][72];

    const int tid  = threadIdx.x;
    const int wave = tid >> 6;
    const int lane = tid & 63;
    const int q    = lane >> 4;      // quad 0..3
    const int rl   = lane & 15;
    const int n0   = blockIdx.x * 64;
    const int ch   = wave * 16 + rl; // channel within gate

    // ---- resident weight B-fragments (bf16), exp2-prefolded scales ----
    const float S1 = 1.44269504088896341f;   // log2(e)
    const float S2 = 2.88539008177792682f;   // 2*log2(e)
    short8 whhf[3][4];   // [gate][kc] K=128
    short8 wihf[3][2];   // [gate][kc] K=64
#pragma unroll
    for (int g = 0; g < 3; g++) {
        const float gs = (g == 2) ? S2 : S1;
        int row = g * 128 + ch;
#pragma unroll
        for (int kc = 0; kc < 4; kc++) {
            const float* p = w_hh + row * HID + kc * 32 + q * 8;
            whhf[g][kc] = pack8s(*(const float4*)p, *(const float4*)(p + 4), gs);
        }
#pragma unroll
        for (int kc = 0; kc < 2; kc++) {
            const float* p = w_ih + row * FIN + kc * 32 + q * 8;
            wihf[g][kc] = pack8s(*(const float4*)p, *(const float4*)(p + 4), gs);
        }
    }

    // per-lane biases (prefolded)
    const float br  = (b_ih[ch] + b_hh[ch]) * S1;
    const float bz  = (b_ih[128 + ch] + b_hh[128 + ch]) * S1;
    const float bin = b_ih[256 + ch] * S2;
    const float bhn = b_hh[256 + ch] * S2;

    // staging assignment: thread owns 4 consecutive floats of a 32x64 tile
    const int sn = tid >> 4;          // node-in-group 0..31
    const int sk = (tid & 15) * 4;    // k 0..60
    int g0n = n0 + sn;      if (g0n > N_NODES - 1) g0n = N_NODES - 1;
    int g1n = n0 + 32 + sn; if (g1n > N_NODES - 1) g1n = N_NODES - 1;
    const float* xs0 = x + (size_t)g0n * SEQ * FIN + sk;
    const float* xs1 = x + (size_t)g1n * SEQ * FIN + sk;

    // h state: lane holds (node-in-group = mt*16 + q*4 + r, this ch)
    float hreg[2][2][4];   // [group][mt][r]
#pragma unroll
    for (int g = 0; g < 2; g++)
#pragma unroll
        for (int mt = 0; mt < 2; mt++)
#pragma unroll
            for (int r = 0; r < 4; r++) hreg[g][mt][r] = 0.f;

    // cross-phase register carry: packed h of previous phase + staged x
    unsigned hp01[2], hp23[2];
    float4 xhold;

    // prologue: stage x(g0,t=0) into LDS; preload x(g1,t=0) into xhold
    {
        float4 v = *(const float4*)(xs0);
        int2 pv;
        pv.x = (int)bfpk(v.x, v.y);
        pv.y = (int)bfpk(v.z, v.w);
        *(int2*)&xB[0][0][sn][sk] = pv;
    }
    xhold = *(const float4*)(xs1);
    BAR();

// One phase: group G, timestep t.
//   DO_HW/HWB : write prev-phase h (group G^1) into hA[G^1][HWB]
//   DO_XW/XWB : write xhold (x for group G^1) into xB[G^1][XWB]
//   DO_XL/XLP : issue global load of next x for THIS group into xhold
#define GRU_PHASE(G, DO_HW, HWB, DO_XW, XWB, DO_XL, XLP)                          \
    {                                                                             \
        const int rb = (t - 1) & 1;                                               \
        short8 xf[2][2], hf[2][4];                                                \
        _Pragma("unroll")                                                         \
        for (int mt = 0; mt < 2; mt++)                                            \
            _Pragma("unroll")                                                     \
            for (int kc = 0; kc < 2; kc++)                                        \
                xf[mt][kc] = *(const short8*)&xB[G][t & 1][mt * 16 + rl][kc * 32 + q * 8]; \
        if (t > 0) {                                                              \
            _Pragma("unroll")                                                     \
            for (int mt = 0; mt < 2; mt++)                                        \
                _Pragma("unroll")                                                 \
                for (int kc = 0; kc < 4; kc++)                                    \
                    hf[mt][kc] = *(const short8*)&hA[G][rb][mt * 16 + rl][kc * 32 + q * 8]; \
        }                                                                         \
        /* deferred writes: hidden under the frag-read latency */                 \
        if (DO_HW) {                                                              \
            _Pragma("unroll")                                                     \
            for (int mt = 0; mt < 2; mt++) {                                      \
                const int nb = mt * 16 + q * 4;                                   \
                hA[G ^ 1][HWB][nb + 0][ch] = (short)(hp01[mt] & 0xFFFF);          \
                hA[G ^ 1][HWB][nb + 1][ch] = (short)(hp01[mt] >> 16);             \
                hA[G ^ 1][HWB][nb + 2][ch] = (short)(hp23[mt] & 0xFFFF);          \
                hA[G ^ 1][HWB][nb + 3][ch] = (short)(hp23[mt] >> 16);             \
            }                                                                     \
        }                                                                         \
        if (DO_XW) {                                                              \
            int2 pv;                                                              \
            pv.x = (int)bfpk(xhold.x, xhold.y);                                   \
            pv.y = (int)bfpk(xhold.z, xhold.w);                                   \
            *(int2*)&xB[G ^ 1][XWB][sn][sk] = pv;                                 \
        }                                                                         \
        if (DO_XL) xhold = *(const float4*)(XLP);   /* consumed next phase */     \
        f32x4 accr[2], accz[2], accin[2], acchn[2];                               \
        _Pragma("unroll")                                                         \
        for (int mt = 0; mt < 2; mt++) {                                          \
            accr[mt] = (f32x4)0.f; accz[mt] = (f32x4)0.f;                         \
            accin[mt] = (f32x4)0.f; acchn[mt] = (f32x4)0.f;                       \
            _Pragma("unroll")                                                     \
            for (int kc = 0; kc < 2; kc++) {                                      \
                accr[mt]  = __builtin_amdgcn_mfma_f32_16x16x32_bf16(xf[mt][kc], wihf[0][kc], accr[mt], 0, 0, 0);  \
                accz[mt]  = __builtin_amdgcn_mfma_f32_16x16x32_bf16(xf[mt][kc], wihf[1][kc], accz[mt], 0, 0, 0);  \
                accin[mt] = __builtin_amdgcn_mfma_f32_16x16x32_bf16(xf[mt][kc], wihf[2][kc], accin[mt], 0, 0, 0); \
            }                                                                     \
            if (t > 0) {                                                          \
                _Pragma("unroll")                                                 \
                for (int kc = 0; kc < 4; kc++) {                                  \
                    accr[mt]  = __builtin_amdgcn_mfma_f32_16x16x32_bf16(hf[mt][kc], whhf[0][kc], accr[mt], 0, 0, 0);  \
                    accz[mt]  = __builtin_amdgcn_mfma_f32_16x16x32_bf16(hf[mt][kc], whhf[1][kc], accz[mt], 0, 0, 0);  \
                    acchn[mt] = __builtin_amdgcn_mfma_f32_16x16x32_bf16(hf[mt][kc], whhf[2][kc], acchn[mt], 0, 0, 0); \
                }                                                                 \
            }                                                                     \
        }                                                                         \
        _Pragma("unroll")                                                         \
        for (int mt = 0; mt < 2; mt++) {                                          \
            float rg[4], zg[4], et[4], hv[4];                                     \
            _Pragma("unroll")                                                     \
            for (int r = 0; r < 4; r++) {                                         \
                float er = ex2(fminf(-(accr[mt][r] + br), 60.f));                 \
                float ez = ex2(fminf(-(accz[mt][r] + bz), 60.f));                 \
                float dr = er + 1.f, dz = ez + 1.f;                               \
                float ip = frcp(dr * dz);                                         \
                rg[r] = dz * ip; zg[r] = dr * ip;                                 \
                float ap = accin[mt][r] + bin + rg[r] * (acchn[mt][r] + bhn);     \
                et[r] = ex2(fminf(ap, 120.f));                                    \
            }                                                                     \
            _Pragma("unroll")                                                     \
            for (int pr = 0; pr < 2; pr++) {                                      \
                float d0 = et[2 * pr] + 1.f, d1 = et[2 * pr + 1] + 1.f;           \
                float ipt = frcp(d0 * d1);                                        \
                float nn0 = 1.f - 2.f * (ipt * d1);                               \
                float nn1 = 1.f - 2.f * (ipt * d0);                               \
                float h0 = zg[2 * pr]     * (hreg[G][mt][2 * pr]     - nn0) + nn0; \
                float h1 = zg[2 * pr + 1] * (hreg[G][mt][2 * pr + 1] - nn1) + nn1; \
                hreg[G][mt][2 * pr] = h0; hreg[G][mt][2 * pr + 1] = h1;           \
                hv[2 * pr] = h0; hv[2 * pr + 1] = h1;                             \
            }                                                                     \
            hp01[mt] = bfpk(hv[0], hv[1]);                                        \
            hp23[mt] = bfpk(hv[2], hv[3]);                                        \
        }                                                                         \
        BAR();                                                                    \
    }

    for (int t = 0; t < SEQ; t++) {
        // phase (g=0,t): write h(g1,t-1)->hA[1][(t-1)&1]; write x(g1,t)->xB[1][t&1]
        GRU_PHASE(0, (t > 0), ((t - 1) & 1), 1, (t & 1),
                  (t + 1 < SEQ), (xs0 + (t + 1) * FIN))
        // phase (g=1,t): write h(g0,t)->hA[0][t&1]; write x(g0,t+1)->xB[0][(t+1)&1]
        GRU_PHASE(1, 1, (t & 1), (t + 1 < SEQ), ((t + 1) & 1),
                  (t + 1 < SEQ), (xs1 + (t + 1) * FIN))
    }
#undef GRU_PHASE

    // final h to global (fp32), straight from registers
#pragma unroll
    for (int g = 0; g < 2; g++)
#pragma unroll
        for (int mt = 0; mt < 2; mt++)
#pragma unroll
            for (int r = 0; r < 4; r++)
                hout[(size_t)(n0 + g * 32 + mt * 16 + q * 4 + r) * HID + ch] = hreg[g][mt][r];
}

// ---------------------------------------------------------------------------
// weight prep for GAT projections: w[g][k] -> [k][g]
// ---------------------------------------------------------------------------
__global__ void prep_weights(const float* __restrict__ g1w, const float* __restrict__ g2w,
                             float* __restrict__ g1T, float* __restrict__ g2T)
{
    int i = blockIdx.x * 256 + threadIdx.x;
    if (i < 128 * 128) {
        int k = i >> 7, g = i & 127;
        g1T[i] = g1w[g * 128 + k];
        g2T[i] = g2w[g * 128 + k];
    }
}

// ---------------------------------------------------------------------------
// CSR build
// ---------------------------------------------------------------------------
__global__ void count_edges(const int* __restrict__ dst, int* __restrict__ deg, int e)
{
    int i = blockIdx.x * 256 + threadIdx.x;
    if (i < e) atomicAdd(&deg[dst[i]], 1);
}

__device__ __forceinline__ int block_scan_inc(int v)
{
    int tid = threadIdx.x, lane = tid & 63, w = tid >> 6;
#pragma unroll
    for (int off = 1; off < 64; off <<= 1) {
        int tmp = __shfl_up(v, off, 64);
        if (lane >= off) v += tmp;
    }
    __shared__ int wsum[4];
    if (lane == 63) wsum[w] = v;
    __syncthreads();
    int add = 0;
    for (int i = 0; i < w; i++) add += wsum[i];
    return v + add;
}

__global__ void scan_block_sums(const int* __restrict__ deg, int* __restrict__ bsum, int n)
{
    int i = blockIdx.x * 256 + threadIdx.x;
    int v = (i < n) ? deg[i] : 0;
#pragma unroll
    for (int off = 32; off >= 1; off >>= 1) v += __shfl_xor(v, off, 64);
    __shared__ int ws[4];
    if ((threadIdx.x & 63) == 0) ws[threadIdx.x >> 6] = v;
    __syncthreads();
    if (threadIdx.x == 0) bsum[blockIdx.x] = ws[0] + ws[1] + ws[2] + ws[3];
}

__global__ void scan_bsum(int* __restrict__ bsum, int nb)
{
    int tid = threadIdx.x;
    int v = (tid < nb) ? bsum[tid] : 0;
    v = block_scan_inc(v);
    if (tid < nb) bsum[tid] = v;
}

__global__ void scan_final(const int* __restrict__ deg, const int* __restrict__ bsum,
                           int* __restrict__ rp, int n)
{
    int i = blockIdx.x * 256 + threadIdx.x;
    int v = (i < n) ? deg[i] : 0;
    int s = block_scan_inc(v);
    int add = (blockIdx.x > 0) ? bsum[blockIdx.x - 1] : 0;
    if (i < n) rp[i + 1] = s + add;
    if (i == 0) rp[0] = 0;
}

__global__ void fill_edges(const int* __restrict__ src, const int* __restrict__ dst,
                           const int* __restrict__ rp, int* __restrict__ cur,
                           int* __restrict__ col, int e)
{
    int i = blockIdx.x * 256 + threadIdx.x;
    if (i < e) {
        int d = dst[i];
        int pos = atomicAdd(&cur[d], 1);
        col[rp[d] + pos] = src[i];
    }
}

// ---------------------------------------------------------------------------
// GAT projection + attention coefficients, fused.
// hp = x @ wT (fp32 accum); writes fp16-packed feature rows (hph) and
// per-(node,head) a_src/a_dst dots (as_, ad_). 32 nodes/block.
// ---------------------------------------------------------------------------
__global__ __launch_bounds__(256) void proj_attn(
    const float* __restrict__ x, const float* __restrict__ wT,
    const float* __restrict__ a_src, const float* __restrict__ a_dst,
    unsigned* __restrict__ hph, float* __restrict__ as_, float* __restrict__ ad_)
{
    __shared__ float xt[32][33];
    __shared__ float wt[32][128];
    __shared__ float ot[32][132];     // 132: 16B-aligned rows for float4 reads
    const int tid = threadIdx.x;
    const int tx = tid & 7;       // 8 node groups of 4
    const int ty = tid >> 3;      // 32 out groups of 4
    const int n0 = blockIdx.x * 32;
    float acc[4][4];
#pragma unroll
    for (int i = 0; i < 4; i++)
#pragma unroll
        for (int j = 0; j < 4; j++) acc[i][j] = 0.f;

    for (int k0 = 0; k0 < 128; k0 += 32) {
        __syncthreads();
#pragma unroll
        for (int i = 0; i < 4; i++) {
            int flat = tid + i * 256;
            int n = flat >> 5, k = flat & 31;
            xt[n][k] = x[(n0 + n) * HID + k0 + k];
        }
#pragma unroll
        for (int i = 0; i < 16; i++) {
            int flat = tid + i * 256;
            int kk = flat >> 7, g = flat & 127;
            wt[kk][g] = wT[(k0 + kk) * HID + g];
        }
        __syncthreads();
#pragma unroll 8
        for (int kk = 0; kk < 32; kk++) {
            float xv[4];
#pragma unroll
            for (int i = 0; i < 4; i++) xv[i] = xt[tx * 4 + i][kk];
            float4 wv = *(const float4*)&wt[kk][ty * 4];
#pragma unroll
            for (int i = 0; i < 4; i++) {
                acc[i][0] = fmaf(xv[i], wv.x, acc[i][0]);
                acc[i][1] = fmaf(xv[i], wv.y, acc[i][1]);
                acc[i][2] = fmaf(xv[i], wv.z, acc[i][2]);
                acc[i][3] = fmaf(xv[i], wv.w, acc[i][3]);
            }
        }
    }
    // epilogue: fp16-packed store + LDS tile for attention dots
#pragma unroll
    for (int i = 0; i < 4; i++) {
        int node = tx * 4 + i;
        ot[node][ty * 4 + 0] = acc[i][0];
        ot[node][ty * 4 + 1] = acc[i][1];
        ot[node][ty * 4 + 2] = acc[i][2];
        ot[node][ty * 4 + 3] = acc[i][3];
        uint2 pv;
        pv.x = hfpk(acc[i][0], acc[i][1]);
        pv.y = hfpk(acc[i][2], acc[i][3]);
        *(uint2*)&hph[(size_t)(n0 + node) * 64 + ty * 2] = pv;
    }
    __syncthreads();
    if (tid < 128) {
        int node = tid >> 2, head = tid & 3;
        const float* ar = a_src + head * 32;
        const float* br = a_dst + head * 32;
        float s = 0.f, d = 0.f;
#pragma unroll
        for (int j = 0; j < 32; j += 4) {
            float4 hv = *(const float4*)&ot[node][head * 32 + j];
            float4 av = *(const float4*)&ar[j];
            float4 bv = *(const float4*)&br[j];
            s += hv.x * av.x + hv.y * av.y + hv.z * av.z + hv.w * av.w;
            d += hv.x * bv.x + hv.y * bv.y + hv.z * bv.z + hv.w * bv.w;
        }
        as_[(n0 + node) * 4 + head] = s;
        ad_[(n0 + node) * 4 + head] = d;
    }
}

// ---------------------------------------------------------------------------
// GAT aggregation: one wave per dst node, CSR + implicit self-loop.
// Features gathered as fp16 pairs: lane owns channels (2*lane, 2*lane+1),
// one dword per edge per lane, coalesced. No max-pass (logits O(5), fp32 exp
// safe; shift is a mathematical no-op). CLF: classifier fused.
// ---------------------------------------------------------------------------
template <bool CLF>
__global__ __launch_bounds__(256) void gat_agg(
    const unsigned* __restrict__ hph, const float* __restrict__ as_,
    const float* __restrict__ ad_, const int* __restrict__ rp,
    const int* __restrict__ col, const float* __restrict__ bias,
    float* __restrict__ out, const float* __restrict__ cw,
    const float* __restrict__ cb, int n_nodes)
{
    __shared__ float exl[4][AGG_CAP][4];
    const int widx = threadIdx.x >> 6;
    const int lane = threadIdx.x & 63;
    const int n = blockIdx.x * 4 + widx;
    if (n >= n_nodes) return;

    const int e0 = rp[n], e1 = rp[n + 1];
    const int deg = e1 - e0;
    float4 adv = *(const float4*)&ad_[n * 4];
    float4 asn = *(const float4*)&as_[n * 4];
    // self-loop exp
    float xs0 = __expf(lrelu02(asn.x + adv.x)), xs1 = __expf(lrelu02(asn.y + adv.y));
    float xs2 = __expf(lrelu02(asn.z + adv.z)), xs3 = __expf(lrelu02(asn.w + adv.w));

    // phase A: exp per edge (lane-strided), cache in LDS, accumulate denoms
    float d0 = 0.f, d1 = 0.f, d2 = 0.f, d3 = 0.f;
    for (int e = e0 + lane; e < e1; e += 64) {
        int s = col[e];
        float4 a = *(const float4*)&as_[s * 4];
        float x0 = __expf(lrelu02(a.x + adv.x));
        float x1 = __expf(lrelu02(a.y + adv.y));
        float x2 = __expf(lrelu02(a.z + adv.z));
        float x3 = __expf(lrelu02(a.w + adv.w));
        int idx = e - e0;
        if (idx < AGG_CAP) {
            exl[widx][idx][0] = x0; exl[widx][idx][1] = x1;
            exl[widx][idx][2] = x2; exl[widx][idx][3] = x3;
        }
        d0 += x0; d1 += x1; d2 += x2; d3 += x3;
    }
#pragma unroll
    for (int off = 32; off >= 1; off >>= 1) {
        d0 += __shfl_xor(d0, off, 64);
        d1 += __shfl_xor(d1, off, 64);
        d2 += __shfl_xor(d2, off, 64);
        d3 += __shfl_xor(d3, off, 64);
    }
    d0 += xs0; d1 += xs1; d2 += xs2; d3 += xs3;
    float i0 = frcp(d0 + 1e-16f), i1 = frcp(d1 + 1e-16f);
    float i2 = frcp(d2 + 1e-16f), i3 = frcp(d3 + 1e-16f);

    // phase B: lane owns channel pair (2*lane, 2*lane+1); head = lane>>4
    const int head = lane >> 4;
    float invh = (head == 0) ? i0 : (head == 1) ? i1 : (head == 2) ? i2 : i3;
    float exsh = (head == 0) ? xs0 : (head == 1) ? xs1 : (head == 2) ? xs2 : xs3;
    float adh  = (head == 0) ? adv.x : (head == 1) ? adv.y : (head == 2) ? adv.z : adv.w;

    float2 sv = h2f2(hph[(size_t)n * 64 + lane]);
    float acc0 = exsh * sv.x;
    float acc1 = exsh * sv.y;

    if (deg <= AGG_CAP) {
        int e = e0;
        for (; e + 4 <= e1; e += 4) {
            int s_[4]; float w_[4]; unsigned u_[4];
#pragma unroll
            for (int u = 0; u < 4; u++) {
                s_[u] = col[e + u];
                w_[u] = exl[widx][e + u - e0][head];
            }
#pragma unroll
            for (int u = 0; u < 4; u++)
                u_[u] = hph[(size_t)s_[u] * 64 + lane];
#pragma unroll
            for (int u = 0; u < 4; u++) {
                float2 f = h2f2(u_[u]);
                acc0 = fmaf(w_[u], f.x, acc0);
                acc1 = fmaf(w_[u], f.y, acc1);
            }
        }
        for (; e < e1; e++) {
            int s = col[e];
            float w = exl[widx][e - e0][head];
            float2 f = h2f2(hph[(size_t)s * 64 + lane]);
            acc0 = fmaf(w, f.x, acc0);
            acc1 = fmaf(w, f.y, acc1);
        }
    } else {
        for (int e = e0; e < e1; e++) {
            int s = col[e];
            int idx = e - e0;
            float w;
            if (idx < AGG_CAP) w = exl[widx][idx][head];
            else               w = __expf(lrelu02(as_[s * 4 + head] + adh));
            float2 f = h2f2(hph[(size_t)s * 64 + lane]);
            acc0 = fmaf(w, f.x, acc0);
            acc1 = fmaf(w, f.y, acc1);
        }
    }

    float2 b2 = *(const float2*)&bias[2 * lane];
    float o0 = eluf_(acc0 * invh + b2.x);
    float o1 = eluf_(acc1 * invh + b2.y);
    if (CLF) {
        float2 cwv = *(const float2*)&cw[2 * lane];
        float v = o0 * cwv.x + o1 * cwv.y;
#pragma unroll
        for (int off = 32; off >= 1; off >>= 1) v += __shfl_xor(v, off, 64);
        if (lane == 0) out[n] = sigmoidf_(v + cb[0]);
    } else {
        *(float2*)&out[(size_t)n * HID + 2 * lane] = make_float2(o0, o1);
    }
}

// ---------------------------------------------------------------------------
extern "C" void kernel_launch(void* const* d_in, const int* in_sizes, int n_in,
                              void* d_out, int out_size, void* d_ws, size_t ws_size,
                              hipStream_t stream)
{
    const float* x     = (const float*)d_in[0];
    const int*   ei    = (const int*)d_in[1];
    const float* w_ih  = (const float*)d_in[2];
    const float* w_hh  = (const float*)d_in[3];
    const float* b_ih  = (const float*)d_in[4];
    const float* b_hh  = (const float*)d_in[5];
    const float* g1w   = (const float*)d_in[6];
    const float* g1as  = (const float*)d_in[7];
    const float* g1ad  = (const float*)d_in[8];
    const float* g1b   = (const float*)d_in[9];
    const float* g2w   = (const float*)d_in[10];
    const float* g2as  = (const float*)d_in[11];
    const float* g2ad  = (const float*)d_in[12];
    const float* g2b   = (const float*)d_in[13];
    const float* cw    = (const float*)d_in[14];
    const float* cb    = (const float*)d_in[15];
    float* out = (float*)d_out;

    char* wsb = (char*)d_ws;
    size_t off = 0;
    auto alc = [&](size_t bytes) { size_t o = off; off += (bytes + 255) & ~(size_t)255; return o; };

    float*    bufA = (float*)(wsb + alc((size_t)NP * HID * 4));      // GRU h
    float*    bufC = (float*)(wsb + alc((size_t)NP * HID * 4));      // layer-1 out
    unsigned* hph  = (unsigned*)(wsb + alc((size_t)NP * 64 * 4));    // fp16-packed features
    float*    as_  = (float*)(wsb + alc((size_t)NP * 4 * 4));
    float*    ad_  = (float*)(wsb + alc((size_t)NP * 4 * 4));
    float*    g1T  = (float*)(wsb + alc((size_t)128 * 128 * 4));
    float*    g2T  = (float*)(wsb + alc((size_t)128 * 128 * 4));
    int*      rp   = (int*)(wsb + alc((size_t)(N_NODES + 1) * 4));
    int*      deg  = (int*)(wsb + alc((size_t)N_NODES * 4));
    int*      cur  = (int*)(wsb + alc((size_t)N_NODES * 4));
    int*      col  = (int*)(wsb + alc((size_t)NEDGE * 4));
    int*      bsum = (int*)(wsb + alc((size_t)256 * 4));

    const int* src = ei;
    const int* dst = ei + NEDGE;

    hipMemsetAsync(deg, 0, (size_t)N_NODES * 4, stream);
    hipMemsetAsync(cur, 0, (size_t)N_NODES * 4, stream);

    prep_weights<<<64, 256, 0, stream>>>(g1w, g2w, g1T, g2T);

    // CSR build (reused by both GAT layers)
    count_edges<<<NEDGE / 256, 256, 0, stream>>>(dst, deg, NEDGE);
    scan_block_sums<<<NB_SCAN, 256, 0, stream>>>(deg, bsum, N_NODES);
    scan_bsum<<<1, 256, 0, stream>>>(bsum, NB_SCAN);
    scan_final<<<NB_SCAN, 256, 0, stream>>>(deg, bsum, rp, N_NODES);
    fill_edges<<<NEDGE / 256, 256, 0, stream>>>(src, dst, rp, cur, col, NEDGE);

    // fused GRU (all 16 steps), bf16 MFMA, A/B pipelined, h -> bufA
    gru_fused<<<NP / 64, 512, 0, stream>>>(x, w_ih, w_hh, b_ih, b_hh, bufA);

    // GAT layer 1: bufA -> hph/as_/ad_ (proj+attn) -> bufC (agg+elu)
    proj_attn<<<NP / 32, 256, 0, stream>>>(bufA, g1T, g1as, g1ad, hph, as_, ad_);
    gat_agg<false><<<(N_NODES + 3) / 4, 256, 0, stream>>>(hph, as_, ad_, rp, col, g1b, bufC,
                                                          nullptr, nullptr, N_NODES);

    // GAT layer 2: bufC -> hph/as_/ad_; agg fused with classifier -> out
    proj_attn<<<NP / 32, 256, 0, stream>>>(bufC, g2T, g2as, g2ad, hph, as_, ad_);
    gat_agg<true><<<(N_NODES + 3) / 4, 256, 0, stream>>>(hph, as_, ad_, rp, col, g2b, out,
                                                         cw, cb, N_NODES);
}

// Round 4
// 828.541 us; speedup vs baseline: 1.6843x; 1.0148x over previous
//
#include <hip/hip_runtime.h>
#include <hip/hip_bf16.h>
#include <hip/hip_fp16.h>
#include <math.h>

#define N_NODES 50000
#define NP      50048          // padded node count (multiple of 64)
#define SEQ     16
#define FIN     64
#define HID     128
#define NEDGE   1600000
#define NB_SCAN 196            // ceil(50000/256)
#define AGG_CAP 96

typedef __attribute__((ext_vector_type(8))) short short8;   // 8 bf16 = 4 VGPRs
typedef __attribute__((ext_vector_type(4))) float f32x4;

__device__ __forceinline__ float lrelu02(float v) { return v > 0.f ? v : 0.2f * v; }
__device__ __forceinline__ float frcp(float v) { return __builtin_amdgcn_rcpf(v); }
__device__ __forceinline__ float ex2(float v) { return __builtin_amdgcn_exp2f(v); }
__device__ __forceinline__ float sigmoidf_(float v) { return frcp(1.f + __expf(-v)); }
__device__ __forceinline__ float eluf_(float v) { return v > 0.f ? v : (__expf(v) - 1.f); }

// packed fp32x2 -> bf16x2 (v_cvt_pk_bf16_f32 on gfx950), RNE
__device__ __forceinline__ unsigned bfpk(float lo, float hi) {
    union { __hip_bfloat162 h; unsigned u; } c;
    c.h = __float22bfloat162_rn(make_float2(lo, hi));
    return c.u;
}
// packed fp32x2 -> fp16x2
__device__ __forceinline__ unsigned hfpk(float lo, float hi) {
    union { __half2 h; unsigned u; } c;
    c.h = __float22half2_rn(make_float2(lo, hi));
    return c.u;
}
__device__ __forceinline__ float2 h2f2(unsigned u) {
    union { unsigned u; __half2 h; } c;
    c.u = u;
    return __half22float2(c.h);
}
// pack 8 floats (scaled) to bf16x8
__device__ __forceinline__ short8 pack8s(float4 a, float4 b, float s) {
    union { short8 sv; unsigned u[4]; } r;
    r.u[0] = bfpk(a.x * s, a.y * s); r.u[1] = bfpk(a.z * s, a.w * s);
    r.u[2] = bfpk(b.x * s, b.y * s); r.u[3] = bfpk(b.z * s, b.w * s);
    return r.sv;
}

// raw barrier: LDS-visibility only (no vmcnt drain -> x prefetch spans phases)
#define BAR() do { asm volatile("s_waitcnt lgkmcnt(0)" ::: "memory"); \
                   __builtin_amdgcn_s_barrier(); } while (0)

// ---------------------------------------------------------------------------
// Fused GRU, R4: cross-phase gate deferral (MFMA || VALU pipeline).
// One block = 64 nodes = two 32-node groups, 512 threads, 2 phases/step.
//
// R3's pipe accounting showed ~88% of wall = LDS(32%)+VALU(36%)+MFMA(19%)
// with ~zero overlap: barrier-lockstep waves all hit the same pipe at the
// same time, and per-wave the chain LDS->MFMA->gate is serial. Fix: phase
// (G,t) runs {frag reads G, MFMAs G -> acc bank G} plus the GATE MATH FOR
// THE PREVIOUS PHASE's accumulators (bank G^1, register-only, no deps on
// this phase's LDS/MFMA) -> compiler can overlap VALU with LDS latency and
// MFMA execution. h-write timing vs barriers is identical to R3 (write in
// phase p+1, read at p+2 top). Final bank gated in epilogue.
// Cost: 2nd acc bank (+32 VGPR) -> ~1 block/CU. R0 vs R1 showed occupancy
// is not the lever (3 blk 278us vs 2 blk 251us); in-wave ILP is the bet.
// ---------------------------------------------------------------------------
__global__ __launch_bounds__(512, 2) void gru_fused(
    const float* __restrict__ x,     // [N][16][64]
    const float* __restrict__ w_ih,  // [384][64]
    const float* __restrict__ w_hh,  // [384][128]
    const float* __restrict__ b_ih,  // [384]
    const float* __restrict__ b_hh,  // [384]
    float* __restrict__ hout)        // [NP][128]
{
    // [group][buf][node][ch], 16B-aligned rows
    __shared__ __align__(16) short hA[2][2][32][136];
    __shared__ __align__(16) short xB[2][2][32][72];

    const int tid  = threadIdx.x;
    const int wave = tid >> 6;
    const int lane = tid & 63;
    const int q    = lane >> 4;      // quad 0..3
    const int rl   = lane & 15;
    const int n0   = blockIdx.x * 64;
    const int ch   = wave * 16 + rl; // channel within gate

    // ---- resident weight B-fragments (bf16), exp2-prefolded scales ----
    const float S1 = 1.44269504088896341f;   // log2(e)
    const float S2 = 2.88539008177792682f;   // 2*log2(e)
    short8 whhf[3][4];   // [gate][kc] K=128
    short8 wihf[3][2];   // [gate][kc] K=64
#pragma unroll
    for (int g = 0; g < 3; g++) {
        const float gs = (g == 2) ? S2 : S1;
        int row = g * 128 + ch;
#pragma unroll
        for (int kc = 0; kc < 4; kc++) {
            const float* p = w_hh + row * HID + kc * 32 + q * 8;
            whhf[g][kc] = pack8s(*(const float4*)p, *(const float4*)(p + 4), gs);
        }
#pragma unroll
        for (int kc = 0; kc < 2; kc++) {
            const float* p = w_ih + row * FIN + kc * 32 + q * 8;
            wihf[g][kc] = pack8s(*(const float4*)p, *(const float4*)(p + 4), gs);
        }
    }

    // per-lane biases (prefolded)
    const float br  = (b_ih[ch] + b_hh[ch]) * S1;
    const float bz  = (b_ih[128 + ch] + b_hh[128 + ch]) * S1;
    const float bin = b_ih[256 + ch] * S2;
    const float bhn = b_hh[256 + ch] * S2;

    // staging assignment: thread owns 4 consecutive floats of a 32x64 tile
    const int sn = tid >> 4;          // node-in-group 0..31
    const int sk = (tid & 15) * 4;    // k 0..60
    int g0n = n0 + sn;      if (g0n > N_NODES - 1) g0n = N_NODES - 1;
    int g1n = n0 + 32 + sn; if (g1n > N_NODES - 1) g1n = N_NODES - 1;
    const float* xs0 = x + (size_t)g0n * SEQ * FIN + sk;
    const float* xs1 = x + (size_t)g1n * SEQ * FIN + sk;

    // h state: lane holds (node-in-group = mt*16 + q*4 + r, this ch)
    float hreg[2][2][4];   // [group][mt][r]
#pragma unroll
    for (int g = 0; g < 2; g++)
#pragma unroll
        for (int mt = 0; mt < 2; mt++)
#pragma unroll
            for (int r = 0; r < 4; r++) hreg[g][mt][r] = 0.f;

    // two accumulator banks: bank b holds the accs produced by group-b phase
    f32x4 accr[2][2], accz[2][2], accin[2][2], acchn[2][2];  // [bank][mt]
    // two-deep x prefetch: xh[g] = pending x tile for group g
    float4 xh[2];

    // prologue: stage x(g0,0) into LDS; preload x(g1,0) into xh[1]
    {
        float4 v = *(const float4*)(xs0);
        int2 pv;
        pv.x = (int)bfpk(v.x, v.y);
        pv.y = (int)bfpk(v.z, v.w);
        *(int2*)&xB[0][0][sn][sk] = pv;
    }
    xh[1] = *(const float4*)(xs1);
    BAR();

// gate math on acc bank B -> updates hreg[PG]; optional LDS write hA[PG][HWB]
#define GATE_BLOCK(B, PG, DO_HW, HWB)                                             \
    {                                                                             \
        _Pragma("unroll")                                                         \
        for (int mt = 0; mt < 2; mt++) {                                          \
            float rg[4], zg[4], et[4];                                            \
            _Pragma("unroll")                                                     \
            for (int r = 0; r < 4; r++) {                                         \
                float er  = ex2(fminf(-(accr[B][mt][r] + br), 60.f));             \
                float ezv = ex2(fminf(-(accz[B][mt][r] + bz), 60.f));             \
                float dr = er + 1.f, dz = ezv + 1.f;                              \
                float ip = frcp(dr * dz);                                         \
                rg[r] = dz * ip; zg[r] = dr * ip;                                 \
                float ap = accin[B][mt][r] + bin + rg[r] * (acchn[B][mt][r] + bhn); \
                et[r] = ex2(fminf(ap, 120.f));                                    \
            }                                                                     \
            _Pragma("unroll")                                                     \
            for (int pr = 0; pr < 2; pr++) {                                      \
                float dd0 = et[2 * pr] + 1.f, dd1 = et[2 * pr + 1] + 1.f;         \
                float ipt = frcp(dd0 * dd1);                                      \
                float nn0 = 1.f - 2.f * (ipt * dd1);                              \
                float nn1 = 1.f - 2.f * (ipt * dd0);                              \
                float h0 = zg[2 * pr]     * (hreg[PG][mt][2 * pr]     - nn0) + nn0; \
                float h1 = zg[2 * pr + 1] * (hreg[PG][mt][2 * pr + 1] - nn1) + nn1; \
                hreg[PG][mt][2 * pr] = h0; hreg[PG][mt][2 * pr + 1] = h1;         \
            }                                                                     \
            if (DO_HW) {                                                          \
                unsigned u01 = bfpk(hreg[PG][mt][0], hreg[PG][mt][1]);            \
                unsigned u23 = bfpk(hreg[PG][mt][2], hreg[PG][mt][3]);            \
                const int nb = mt * 16 + q * 4;                                   \
                hA[PG][HWB][nb + 0][ch] = (short)(u01 & 0xFFFF);                  \
                hA[PG][HWB][nb + 1][ch] = (short)(u01 >> 16);                     \
                hA[PG][HWB][nb + 2][ch] = (short)(u23 & 0xFFFF);                  \
                hA[PG][HWB][nb + 3][ch] = (short)(u23 >> 16);                     \
            }                                                                     \
        }                                                                         \
    }

// One phase: group G, timestep t (loop var). PG = G^1 (literal).
//   - frag reads for G; issue x(G,t+1) load into xh[G]
//   - MFMAs -> bank G
//   - DO_GATE: gate bank PG (prev phase's accs) -> h of group PG,
//     write hA[PG][HWB] when DO_HW
//   - DO_XW: consume xh[PG] -> xB[PG][XWB]
#define GRU_PHASE(G, PG, DO_GATE, HWB, DO_HW, DO_XW, XWB, XPTR)                   \
    {                                                                             \
        short8 xf[2][2], hf[2][4];                                                \
        _Pragma("unroll")                                                         \
        for (int mt = 0; mt < 2; mt++)                                            \
            _Pragma("unroll")                                                     \
            for (int kc = 0; kc < 2; kc++)                                        \
                xf[mt][kc] = *(const short8*)&xB[G][t & 1][mt * 16 + rl][kc * 32 + q * 8]; \
        if (t > 0) {                                                              \
            _Pragma("unroll")                                                     \
            for (int mt = 0; mt < 2; mt++)                                        \
                _Pragma("unroll")                                                 \
                for (int kc = 0; kc < 4; kc++)                                    \
                    hf[mt][kc] = *(const short8*)&hA[G][(t - 1) & 1][mt * 16 + rl][kc * 32 + q * 8]; \
        }                                                                         \
        if (t + 1 < SEQ) xh[G] = *(const float4*)(XPTR + (t + 1) * FIN);          \
        _Pragma("unroll")                                                         \
        for (int mt = 0; mt < 2; mt++) {                                          \
            accr[G][mt]  = __builtin_amdgcn_mfma_f32_16x16x32_bf16(xf[mt][0], wihf[0][0], (f32x4)0.f, 0, 0, 0); \
            accz[G][mt]  = __builtin_amdgcn_mfma_f32_16x16x32_bf16(xf[mt][0], wihf[1][0], (f32x4)0.f, 0, 0, 0); \
            accin[G][mt] = __builtin_amdgcn_mfma_f32_16x16x32_bf16(xf[mt][0], wihf[2][0], (f32x4)0.f, 0, 0, 0); \
            accr[G][mt]  = __builtin_amdgcn_mfma_f32_16x16x32_bf16(xf[mt][1], wihf[0][1], accr[G][mt], 0, 0, 0); \
            accz[G][mt]  = __builtin_amdgcn_mfma_f32_16x16x32_bf16(xf[mt][1], wihf[1][1], accz[G][mt], 0, 0, 0); \
            accin[G][mt] = __builtin_amdgcn_mfma_f32_16x16x32_bf16(xf[mt][1], wihf[2][1], accin[G][mt], 0, 0, 0); \
            if (t > 0) {                                                          \
                acchn[G][mt] = __builtin_amdgcn_mfma_f32_16x16x32_bf16(hf[mt][0], whhf[2][0], (f32x4)0.f, 0, 0, 0); \
                _Pragma("unroll")                                                 \
                for (int kc = 0; kc < 4; kc++) {                                  \
                    accr[G][mt]  = __builtin_amdgcn_mfma_f32_16x16x32_bf16(hf[mt][kc], whhf[0][kc], accr[G][mt], 0, 0, 0);  \
                    accz[G][mt]  = __builtin_amdgcn_mfma_f32_16x16x32_bf16(hf[mt][kc], whhf[1][kc], accz[G][mt], 0, 0, 0);  \
                }                                                                 \
                _Pragma("unroll")                                                 \
                for (int kc = 1; kc < 4; kc++)                                    \
                    acchn[G][mt] = __builtin_amdgcn_mfma_f32_16x16x32_bf16(hf[mt][kc], whhf[2][kc], acchn[G][mt], 0, 0, 0); \
            } else {                                                              \
                acchn[G][mt] = (f32x4)0.f;                                        \
            }                                                                     \
        }                                                                         \
        if (DO_GATE) GATE_BLOCK(PG, PG, DO_HW, HWB);                              \
        if (DO_XW) {                                                              \
            int2 pv;                                                              \
            pv.x = (int)bfpk(xh[PG].x, xh[PG].y);                                 \
            pv.y = (int)bfpk(xh[PG].z, xh[PG].w);                                 \
            *(int2*)&xB[PG][XWB][sn][sk] = pv;                                    \
        }                                                                         \
        BAR();                                                                    \
    }

    for (int t = 0; t < SEQ; t++) {
        // phase (0,t): MFMA g0 -> bank0; gate bank1 = (g1,t-1) -> hA[1][(t-1)&1];
        //              consume xh[1]=x(g1,t) -> xB[1][t&1]; issue xh[0]=x(g0,t+1)
        GRU_PHASE(0, 1, (t > 0), ((t - 1) & 1), (t > 0), 1, (t & 1), xs0)
        // phase (1,t): MFMA g1 -> bank1; gate bank0 = (g0,t) -> hA[0][t&1];
        //              consume xh[0]=x(g0,t+1) -> xB[0][(t+1)&1]; issue xh[1]
        GRU_PHASE(1, 0, 1, (t & 1), (t + 1 < SEQ), (t + 1 < SEQ), ((t + 1) & 1), xs1)
    }
#undef GRU_PHASE

    // epilogue: gate the final bank (group 1, t=15); no LDS write needed
    GATE_BLOCK(1, 1, 0, 0);
#undef GATE_BLOCK

    // final h to global (fp32), straight from registers
#pragma unroll
    for (int g = 0; g < 2; g++)
#pragma unroll
        for (int mt = 0; mt < 2; mt++)
#pragma unroll
            for (int r = 0; r < 4; r++)
                hout[(size_t)(n0 + g * 32 + mt * 16 + q * 4 + r) * HID + ch] = hreg[g][mt][r];
}

// ---------------------------------------------------------------------------
// weight prep for GAT projections: w[g][k] -> [k][g]
// ---------------------------------------------------------------------------
__global__ void prep_weights(const float* __restrict__ g1w, const float* __restrict__ g2w,
                             float* __restrict__ g1T, float* __restrict__ g2T)
{
    int i = blockIdx.x * 256 + threadIdx.x;
    if (i < 128 * 128) {
        int k = i >> 7, g = i & 127;
        g1T[i] = g1w[g * 128 + k];
        g2T[i] = g2w[g * 128 + k];
    }
}

// ---------------------------------------------------------------------------
// CSR build
// ---------------------------------------------------------------------------
__global__ void count_edges(const int* __restrict__ dst, int* __restrict__ deg, int e)
{
    int i = blockIdx.x * 256 + threadIdx.x;
    if (i < e) atomicAdd(&deg[dst[i]], 1);
}

__device__ __forceinline__ int block_scan_inc(int v)
{
    int tid = threadIdx.x, lane = tid & 63, w = tid >> 6;
#pragma unroll
    for (int off = 1; off < 64; off <<= 1) {
        int tmp = __shfl_up(v, off, 64);
        if (lane >= off) v += tmp;
    }
    __shared__ int wsum[4];
    if (lane == 63) wsum[w] = v;
    __syncthreads();
    int add = 0;
    for (int i = 0; i < w; i++) add += wsum[i];
    return v + add;
}

__global__ void scan_block_sums(const int* __restrict__ deg, int* __restrict__ bsum, int n)
{
    int i = blockIdx.x * 256 + threadIdx.x;
    int v = (i < n) ? deg[i] : 0;
#pragma unroll
    for (int off = 32; off >= 1; off >>= 1) v += __shfl_xor(v, off, 64);
    __shared__ int ws[4];
    if ((threadIdx.x & 63) == 0) ws[threadIdx.x >> 6] = v;
    __syncthreads();
    if (threadIdx.x == 0) bsum[blockIdx.x] = ws[0] + ws[1] + ws[2] + ws[3];
}

__global__ void scan_bsum(int* __restrict__ bsum, int nb)
{
    int tid = threadIdx.x;
    int v = (tid < nb) ? bsum[tid] : 0;
    v = block_scan_inc(v);
    if (tid < nb) bsum[tid] = v;
}

__global__ void scan_final(const int* __restrict__ deg, const int* __restrict__ bsum,
                           int* __restrict__ rp, int n)
{
    int i = blockIdx.x * 256 + threadIdx.x;
    int v = (i < n) ? deg[i] : 0;
    int s = block_scan_inc(v);
    int add = (blockIdx.x > 0) ? bsum[blockIdx.x - 1] : 0;
    if (i < n) rp[i + 1] = s + add;
    if (i == 0) rp[0] = 0;
}

__global__ void fill_edges(const int* __restrict__ src, const int* __restrict__ dst,
                           const int* __restrict__ rp, int* __restrict__ cur,
                           int* __restrict__ col, int e)
{
    int i = blockIdx.x * 256 + threadIdx.x;
    if (i < e) {
        int d = dst[i];
        int pos = atomicAdd(&cur[d], 1);
        col[rp[d] + pos] = src[i];
    }
}

// ---------------------------------------------------------------------------
// GAT projection + attention coefficients, fused.
// hp = x @ wT (fp32 accum); writes fp16-packed feature rows (hph) and
// per-(node,head) a_src/a_dst dots (as_, ad_). 32 nodes/block.
// ---------------------------------------------------------------------------
__global__ __launch_bounds__(256) void proj_attn(
    const float* __restrict__ x, const float* __restrict__ wT,
    const float* __restrict__ a_src, const float* __restrict__ a_dst,
    unsigned* __restrict__ hph, float* __restrict__ as_, float* __restrict__ ad_)
{
    __shared__ float xt[32][33];
    __shared__ float wt[32][128];
    __shared__ float ot[32][132];     // 132: 16B-aligned rows for float4 reads
    const int tid = threadIdx.x;
    const int tx = tid & 7;       // 8 node groups of 4
    const int ty = tid >> 3;      // 32 out groups of 4
    const int n0 = blockIdx.x * 32;
    float acc[4][4];
#pragma unroll
    for (int i = 0; i < 4; i++)
#pragma unroll
        for (int j = 0; j < 4; j++) acc[i][j] = 0.f;

    for (int k0 = 0; k0 < 128; k0 += 32) {
        __syncthreads();
#pragma unroll
        for (int i = 0; i < 4; i++) {
            int flat = tid + i * 256;
            int n = flat >> 5, k = flat & 31;
            xt[n][k] = x[(n0 + n) * HID + k0 + k];
        }
#pragma unroll
        for (int i = 0; i < 16; i++) {
            int flat = tid + i * 256;
            int kk = flat >> 7, g = flat & 127;
            wt[kk][g] = wT[(k0 + kk) * HID + g];
        }
        __syncthreads();
#pragma unroll 8
        for (int kk = 0; kk < 32; kk++) {
            float xv[4];
#pragma unroll
            for (int i = 0; i < 4; i++) xv[i] = xt[tx * 4 + i][kk];
            float4 wv = *(const float4*)&wt[kk][ty * 4];
#pragma unroll
            for (int i = 0; i < 4; i++) {
                acc[i][0] = fmaf(xv[i], wv.x, acc[i][0]);
                acc[i][1] = fmaf(xv[i], wv.y, acc[i][1]);
                acc[i][2] = fmaf(xv[i], wv.z, acc[i][2]);
                acc[i][3] = fmaf(xv[i], wv.w, acc[i][3]);
            }
        }
    }
    // epilogue: fp16-packed store + LDS tile for attention dots
#pragma unroll
    for (int i = 0; i < 4; i++) {
        int node = tx * 4 + i;
        ot[node][ty * 4 + 0] = acc[i][0];
        ot[node][ty * 4 + 1] = acc[i][1];
        ot[node][ty * 4 + 2] = acc[i][2];
        ot[node][ty * 4 + 3] = acc[i][3];
        uint2 pv;
        pv.x = hfpk(acc[i][0], acc[i][1]);
        pv.y = hfpk(acc[i][2], acc[i][3]);
        *(uint2*)&hph[(size_t)(n0 + node) * 64 + ty * 2] = pv;
    }
    __syncthreads();
    if (tid < 128) {
        int node = tid >> 2, head = tid & 3;
        const float* ar = a_src + head * 32;
        const float* br = a_dst + head * 32;
        float s = 0.f, d = 0.f;
#pragma unroll
        for (int j = 0; j < 32; j += 4) {
            float4 hv = *(const float4*)&ot[node][head * 32 + j];
            float4 av = *(const float4*)&ar[j];
            float4 bv = *(const float4*)&br[j];
            s += hv.x * av.x + hv.y * av.y + hv.z * av.z + hv.w * av.w;
            d += hv.x * bv.x + hv.y * bv.y + hv.z * bv.z + hv.w * bv.w;
        }
        as_[(n0 + node) * 4 + head] = s;
        ad_[(n0 + node) * 4 + head] = d;
    }
}

// ---------------------------------------------------------------------------
// GAT aggregation: one wave per dst node, CSR + implicit self-loop.
// Features gathered as fp16 pairs: lane owns channels (2*lane, 2*lane+1),
// one dword per edge per lane, coalesced. No max-pass (logits O(5), fp32 exp
// safe; shift is a mathematical no-op). CLF: classifier fused.
// ---------------------------------------------------------------------------
template <bool CLF>
__global__ __launch_bounds__(256) void gat_agg(
    const unsigned* __restrict__ hph, const float* __restrict__ as_,
    const float* __restrict__ ad_, const int* __restrict__ rp,
    const int* __restrict__ col, const float* __restrict__ bias,
    float* __restrict__ out, const float* __restrict__ cw,
    const float* __restrict__ cb, int n_nodes)
{
    __shared__ float exl[4][AGG_CAP][4];
    const int widx = threadIdx.x >> 6;
    const int lane = threadIdx.x & 63;
    const int n = blockIdx.x * 4 + widx;
    if (n >= n_nodes) return;

    const int e0 = rp[n], e1 = rp[n + 1];
    const int deg = e1 - e0;
    float4 adv = *(const float4*)&ad_[n * 4];
    float4 asn = *(const float4*)&as_[n * 4];
    // self-loop exp
    float xs0 = __expf(lrelu02(asn.x + adv.x)), xs1 = __expf(lrelu02(asn.y + adv.y));
    float xs2 = __expf(lrelu02(asn.z + adv.z)), xs3 = __expf(lrelu02(asn.w + adv.w));

    // phase A: exp per edge (lane-strided), cache in LDS, accumulate denoms
    float d0 = 0.f, d1 = 0.f, d2 = 0.f, d3 = 0.f;
    for (int e = e0 + lane; e < e1; e += 64) {
        int s = col[e];
        float4 a = *(const float4*)&as_[s * 4];
        float x0 = __expf(lrelu02(a.x + adv.x));
        float x1 = __expf(lrelu02(a.y + adv.y));
        float x2 = __expf(lrelu02(a.z + adv.z));
        float x3 = __expf(lrelu02(a.w + adv.w));
        int idx = e - e0;
        if (idx < AGG_CAP) {
            exl[widx][idx][0] = x0; exl[widx][idx][1] = x1;
            exl[widx][idx][2] = x2; exl[widx][idx][3] = x3;
        }
        d0 += x0; d1 += x1; d2 += x2; d3 += x3;
    }
#pragma unroll
    for (int off = 32; off >= 1; off >>= 1) {
        d0 += __shfl_xor(d0, off, 64);
        d1 += __shfl_xor(d1, off, 64);
        d2 += __shfl_xor(d2, off, 64);
        d3 += __shfl_xor(d3, off, 64);
    }
    d0 += xs0; d1 += xs1; d2 += xs2; d3 += xs3;
    float i0 = frcp(d0 + 1e-16f), i1 = frcp(d1 + 1e-16f);
    float i2 = frcp(d2 + 1e-16f), i3 = frcp(d3 + 1e-16f);

    // phase B: lane owns channel pair (2*lane, 2*lane+1); head = lane>>4
    const int head = lane >> 4;
    float invh = (head == 0) ? i0 : (head == 1) ? i1 : (head == 2) ? i2 : i3;
    float exsh = (head == 0) ? xs0 : (head == 1) ? xs1 : (head == 2) ? xs2 : xs3;
    float adh  = (head == 0) ? adv.x : (head == 1) ? adv.y : (head == 2) ? adv.z : adv.w;

    float2 sv = h2f2(hph[(size_t)n * 64 + lane]);
    float acc0 = exsh * sv.x;
    float acc1 = exsh * sv.y;

    if (deg <= AGG_CAP) {
        int e = e0;
        for (; e + 4 <= e1; e += 4) {
            int s_[4]; float w_[4]; unsigned u_[4];
#pragma unroll
            for (int u = 0; u < 4; u++) {
                s_[u] = col[e + u];
                w_[u] = exl[widx][e + u - e0][head];
            }
#pragma unroll
            for (int u = 0; u < 4; u++)
                u_[u] = hph[(size_t)s_[u] * 64 + lane];
#pragma unroll
            for (int u = 0; u < 4; u++) {
                float2 f = h2f2(u_[u]);
                acc0 = fmaf(w_[u], f.x, acc0);
                acc1 = fmaf(w_[u], f.y, acc1);
            }
        }
        for (; e < e1; e++) {
            int s = col[e];
            float w = exl[widx][e - e0][head];
            float2 f = h2f2(hph[(size_t)s * 64 + lane]);
            acc0 = fmaf(w, f.x, acc0);
            acc1 = fmaf(w, f.y, acc1);
        }
    } else {
        for (int e = e0; e < e1; e++) {
            int s = col[e];
            int idx = e - e0;
            float w;
            if (idx < AGG_CAP) w = exl[widx][idx][head];
            else               w = __expf(lrelu02(as_[s * 4 + head] + adh));
            float2 f = h2f2(hph[(size_t)s * 64 + lane]);
            acc0 = fmaf(w, f.x, acc0);
            acc1 = fmaf(w, f.y, acc1);
        }
    }

    float2 b2 = *(const float2*)&bias[2 * lane];
    float o0 = eluf_(acc0 * invh + b2.x);
    float o1 = eluf_(acc1 * invh + b2.y);
    if (CLF) {
        float2 cwv = *(const float2*)&cw[2 * lane];
        float v = o0 * cwv.x + o1 * cwv.y;
#pragma unroll
        for (int off = 32; off >= 1; off >>= 1) v += __shfl_xor(v, off, 64);
        if (lane == 0) out[n] = sigmoidf_(v + cb[0]);
    } else {
        *(float2*)&out[(size_t)n * HID + 2 * lane] = make_float2(o0, o1);
    }
}

// ---------------------------------------------------------------------------
extern "C" void kernel_launch(void* const* d_in, const int* in_sizes, int n_in,
                              void* d_out, int out_size, void* d_ws, size_t ws_size,
                              hipStream_t stream)
{
    const float* x     = (const float*)d_in[0];
    const int*   ei    = (const int*)d_in[1];
    const float* w_ih  = (const float*)d_in[2];
    const float* w_hh  = (const float*)d_in[3];
    const float* b_ih  = (const float*)d_in[4];
    const float* b_hh  = (const float*)d_in[5];
    const float* g1w   = (const float*)d_in[6];
    const float* g1as  = (const float*)d_in[7];
    const float* g1ad  = (const float*)d_in[8];
    const float* g1b   = (const float*)d_in[9];
    const float* g2w   = (const float*)d_in[10];
    const float* g2as  = (const float*)d_in[11];
    const float* g2ad  = (const float*)d_in[12];
    const float* g2b   = (const float*)d_in[13];
    const float* cw    = (const float*)d_in[14];
    const float* cb    = (const float*)d_in[15];
    float* out = (float*)d_out;

    char* wsb = (char*)d_ws;
    size_t off = 0;
    auto alc = [&](size_t bytes) { size_t o = off; off += (bytes + 255) & ~(size_t)255; return o; };

    float*    bufA = (float*)(wsb + alc((size_t)NP * HID * 4));      // GRU h
    float*    bufC = (float*)(wsb + alc((size_t)NP * HID * 4));      // layer-1 out
    unsigned* hph  = (unsigned*)(wsb + alc((size_t)NP * 64 * 4));    // fp16-packed features
    float*    as_  = (float*)(wsb + alc((size_t)NP * 4 * 4));
    float*    ad_  = (float*)(wsb + alc((size_t)NP * 4 * 4));
    float*    g1T  = (float*)(wsb + alc((size_t)128 * 128 * 4));
    float*    g2T  = (float*)(wsb + alc((size_t)128 * 128 * 4));
    int*      rp   = (int*)(wsb + alc((size_t)(N_NODES + 1) * 4));
    int*      deg  = (int*)(wsb + alc((size_t)N_NODES * 4));
    int*      cur  = (int*)(wsb + alc((size_t)N_NODES * 4));
    int*      col  = (int*)(wsb + alc((size_t)NEDGE * 4));
    int*      bsum = (int*)(wsb + alc((size_t)256 * 4));

    const int* src = ei;
    const int* dst = ei + NEDGE;

    hipMemsetAsync(deg, 0, (size_t)N_NODES * 4, stream);
    hipMemsetAsync(cur, 0, (size_t)N_NODES * 4, stream);

    prep_weights<<<64, 256, 0, stream>>>(g1w, g2w, g1T, g2T);

    // CSR build (reused by both GAT layers)
    count_edges<<<NEDGE / 256, 256, 0, stream>>>(dst, deg, NEDGE);
    scan_block_sums<<<NB_SCAN, 256, 0, stream>>>(deg, bsum, N_NODES);
    scan_bsum<<<1, 256, 0, stream>>>(bsum, NB_SCAN);
    scan_final<<<NB_SCAN, 256, 0, stream>>>(deg, bsum, rp, N_NODES);
    fill_edges<<<NEDGE / 256, 256, 0, stream>>>(src, dst, rp, cur, col, NEDGE);

    // fused GRU (all 16 steps), bf16 MFMA, gate-deferred pipeline, h -> bufA
    gru_fused<<<NP / 64, 512, 0, stream>>>(x, w_ih, w_hh, b_ih, b_hh, bufA);

    // GAT layer 1: bufA -> hph/as_/ad_ (proj+attn) -> bufC (agg+elu)
    proj_attn<<<NP / 32, 256, 0, stream>>>(bufA, g1T, g1as, g1ad, hph, as_, ad_);
    gat_agg<false><<<(N_NODES + 3) / 4, 256, 0, stream>>>(hph, as_, ad_, rp, col, g1b, bufC,
                                                          nullptr, nullptr, N_NODES);

    // GAT layer 2: bufC -> hph/as_/ad_; agg fused with classifier -> out
    proj_attn<<<NP / 32, 256, 0, stream>>>(bufC, g2T, g2as, g2ad, hph, as_, ad_);
    gat_agg<true><<<(N_NODES + 3) / 4, 256, 0, stream>>>(hph, as_, ad_, rp, col, g2b, out,
                                                         cw, cb, N_NODES);
}

// Round 5
// 802.581 us; speedup vs baseline: 1.7388x; 1.0323x over previous
//
#include <hip/hip_runtime.h>
#include <hip/hip_bf16.h>
#include <hip/hip_fp16.h>
#include <math.h>

#define N_NODES 50000
#define NP      50048          // padded node count (multiple of 64)
#define SEQ     16
#define FIN     64
#define HID     128
#define NEDGE   1600000
#define NB_SCAN 196            // ceil(50000/256)

typedef __attribute__((ext_vector_type(8))) short short8;      // 8 bf16 = 4 VGPRs
typedef __attribute__((ext_vector_type(8))) _Float16 half8;    // 8 fp16 = 4 VGPRs
typedef __attribute__((ext_vector_type(4))) float f32x4;

__device__ __forceinline__ float lrelu02(float v) { return v > 0.f ? v : 0.2f * v; }
__device__ __forceinline__ float frcp(float v) { return __builtin_amdgcn_rcpf(v); }
__device__ __forceinline__ float ex2(float v) { return __builtin_amdgcn_exp2f(v); }
__device__ __forceinline__ float sigmoidf_(float v) { return frcp(1.f + __expf(-v)); }
__device__ __forceinline__ float eluf_(float v) { return v > 0.f ? v : (__expf(v) - 1.f); }

// packed fp32x2 -> bf16x2 (v_cvt_pk_bf16_f32 on gfx950), RNE
__device__ __forceinline__ unsigned bfpk(float lo, float hi) {
    union { __hip_bfloat162 h; unsigned u; } c;
    c.h = __float22bfloat162_rn(make_float2(lo, hi));
    return c.u;
}
// packed fp32x2 -> fp16x2
__device__ __forceinline__ unsigned hfpk(float lo, float hi) {
    union { __half2 h; unsigned u; } c;
    c.h = __float22half2_rn(make_float2(lo, hi));
    return c.u;
}
__device__ __forceinline__ float2 h2f2(unsigned u) {
    union { unsigned u; __half2 h; } c;
    c.u = u;
    return __half22float2(c.h);
}
// pack 8 floats (scaled) to bf16x8
__device__ __forceinline__ short8 pack8s(float4 a, float4 b, float s) {
    union { short8 sv; unsigned u[4]; } r;
    r.u[0] = bfpk(a.x * s, a.y * s); r.u[1] = bfpk(a.z * s, a.w * s);
    r.u[2] = bfpk(b.x * s, b.y * s); r.u[3] = bfpk(b.z * s, b.w * s);
    return r.sv;
}
// pack 8 floats to fp16x8
__device__ __forceinline__ half8 pack8h(float4 a, float4 b) {
    union { half8 hv; unsigned u[4]; } r;
    r.u[0] = hfpk(a.x, a.y); r.u[1] = hfpk(a.z, a.w);
    r.u[2] = hfpk(b.x, b.y); r.u[3] = hfpk(b.z, b.w);
    return r.hv;
}

// raw barrier: LDS-visibility only (no vmcnt drain -> x prefetch spans phases)
#define BAR() do { asm volatile("s_waitcnt lgkmcnt(0)" ::: "memory"); \
                   __builtin_amdgcn_s_barrier(); } while (0)

// ---------------------------------------------------------------------------
// Fused GRU (unchanged from R4, 233 us): cross-phase gate deferral.
// One block = 64 nodes = two 32-node groups, 512 threads, 2 phases/step.
// ---------------------------------------------------------------------------
__global__ __launch_bounds__(512, 2) void gru_fused(
    const float* __restrict__ x,     // [N][16][64]
    const float* __restrict__ w_ih,  // [384][64]
    const float* __restrict__ w_hh,  // [384][128]
    const float* __restrict__ b_ih,  // [384]
    const float* __restrict__ b_hh,  // [384]
    float* __restrict__ hout)        // [NP][128]
{
    __shared__ __align__(16) short hA[2][2][32][136];
    __shared__ __align__(16) short xB[2][2][32][72];

    const int tid  = threadIdx.x;
    const int wave = tid >> 6;
    const int lane = tid & 63;
    const int q    = lane >> 4;      // quad 0..3
    const int rl   = lane & 15;
    const int n0   = blockIdx.x * 64;
    const int ch   = wave * 16 + rl; // channel within gate

    const float S1 = 1.44269504088896341f;   // log2(e)
    const float S2 = 2.88539008177792682f;   // 2*log2(e)
    short8 whhf[3][4];   // [gate][kc] K=128
    short8 wihf[3][2];   // [gate][kc] K=64
#pragma unroll
    for (int g = 0; g < 3; g++) {
        const float gs = (g == 2) ? S2 : S1;
        int row = g * 128 + ch;
#pragma unroll
        for (int kc = 0; kc < 4; kc++) {
            const float* p = w_hh + row * HID + kc * 32 + q * 8;
            whhf[g][kc] = pack8s(*(const float4*)p, *(const float4*)(p + 4), gs);
        }
#pragma unroll
        for (int kc = 0; kc < 2; kc++) {
            const float* p = w_ih + row * FIN + kc * 32 + q * 8;
            wihf[g][kc] = pack8s(*(const float4*)p, *(const float4*)(p + 4), gs);
        }
    }

    const float br  = (b_ih[ch] + b_hh[ch]) * S1;
    const float bz  = (b_ih[128 + ch] + b_hh[128 + ch]) * S1;
    const float bin = b_ih[256 + ch] * S2;
    const float bhn = b_hh[256 + ch] * S2;

    const int sn = tid >> 4;          // node-in-group 0..31
    const int sk = (tid & 15) * 4;    // k 0..60
    int g0n = n0 + sn;      if (g0n > N_NODES - 1) g0n = N_NODES - 1;
    int g1n = n0 + 32 + sn; if (g1n > N_NODES - 1) g1n = N_NODES - 1;
    const float* xs0 = x + (size_t)g0n * SEQ * FIN + sk;
    const float* xs1 = x + (size_t)g1n * SEQ * FIN + sk;

    float hreg[2][2][4];   // [group][mt][r]
#pragma unroll
    for (int g = 0; g < 2; g++)
#pragma unroll
        for (int mt = 0; mt < 2; mt++)
#pragma unroll
            for (int r = 0; r < 4; r++) hreg[g][mt][r] = 0.f;

    f32x4 accr[2][2], accz[2][2], accin[2][2], acchn[2][2];  // [bank][mt]
    float4 xh[2];

    {
        float4 v = *(const float4*)(xs0);
        int2 pv;
        pv.x = (int)bfpk(v.x, v.y);
        pv.y = (int)bfpk(v.z, v.w);
        *(int2*)&xB[0][0][sn][sk] = pv;
    }
    xh[1] = *(const float4*)(xs1);
    BAR();

#define GATE_BLOCK(B, PG, DO_HW, HWB)                                             \
    {                                                                             \
        _Pragma("unroll")                                                         \
        for (int mt = 0; mt < 2; mt++) {                                          \
            float rg[4], zg[4], et[4];                                            \
            _Pragma("unroll")                                                     \
            for (int r = 0; r < 4; r++) {                                         \
                float er  = ex2(fminf(-(accr[B][mt][r] + br), 60.f));             \
                float ezv = ex2(fminf(-(accz[B][mt][r] + bz), 60.f));             \
                float dr = er + 1.f, dz = ezv + 1.f;                              \
                float ip = frcp(dr * dz);                                         \
                rg[r] = dz * ip; zg[r] = dr * ip;                                 \
                float ap = accin[B][mt][r] + bin + rg[r] * (acchn[B][mt][r] + bhn); \
                et[r] = ex2(fminf(ap, 120.f));                                    \
            }                                                                     \
            _Pragma("unroll")                                                     \
            for (int pr = 0; pr < 2; pr++) {                                      \
                float dd0 = et[2 * pr] + 1.f, dd1 = et[2 * pr + 1] + 1.f;         \
                float ipt = frcp(dd0 * dd1);                                      \
                float nn0 = 1.f - 2.f * (ipt * dd1);                              \
                float nn1 = 1.f - 2.f * (ipt * dd0);                              \
                float h0 = zg[2 * pr]     * (hreg[PG][mt][2 * pr]     - nn0) + nn0; \
                float h1 = zg[2 * pr + 1] * (hreg[PG][mt][2 * pr + 1] - nn1) + nn1; \
                hreg[PG][mt][2 * pr] = h0; hreg[PG][mt][2 * pr + 1] = h1;         \
            }                                                                     \
            if (DO_HW) {                                                          \
                unsigned u01 = bfpk(hreg[PG][mt][0], hreg[PG][mt][1]);            \
                unsigned u23 = bfpk(hreg[PG][mt][2], hreg[PG][mt][3]);            \
                const int nb = mt * 16 + q * 4;                                   \
                hA[PG][HWB][nb + 0][ch] = (short)(u01 & 0xFFFF);                  \
                hA[PG][HWB][nb + 1][ch] = (short)(u01 >> 16);                     \
                hA[PG][HWB][nb + 2][ch] = (short)(u23 & 0xFFFF);                  \
                hA[PG][HWB][nb + 3][ch] = (short)(u23 >> 16);                     \
            }                                                                     \
        }                                                                         \
    }

#define GRU_PHASE(G, PG, DO_GATE, HWB, DO_HW, DO_XW, XWB, XPTR)                   \
    {                                                                             \
        short8 xf[2][2], hf[2][4];                                                \
        _Pragma("unroll")                                                         \
        for (int mt = 0; mt < 2; mt++)                                            \
            _Pragma("unroll")                                                     \
            for (int kc = 0; kc < 2; kc++)                                        \
                xf[mt][kc] = *(const short8*)&xB[G][t & 1][mt * 16 + rl][kc * 32 + q * 8]; \
        if (t > 0) {                                                              \
            _Pragma("unroll")                                                     \
            for (int mt = 0; mt < 2; mt++)                                        \
                _Pragma("unroll")                                                 \
                for (int kc = 0; kc < 4; kc++)                                    \
                    hf[mt][kc] = *(const short8*)&hA[G][(t - 1) & 1][mt * 16 + rl][kc * 32 + q * 8]; \
        }                                                                         \
        if (t + 1 < SEQ) xh[G] = *(const float4*)(XPTR + (t + 1) * FIN);          \
        _Pragma("unroll")                                                         \
        for (int mt = 0; mt < 2; mt++) {                                          \
            accr[G][mt]  = __builtin_amdgcn_mfma_f32_16x16x32_bf16(xf[mt][0], wihf[0][0], (f32x4)0.f, 0, 0, 0); \
            accz[G][mt]  = __builtin_amdgcn_mfma_f32_16x16x32_bf16(xf[mt][0], wihf[1][0], (f32x4)0.f, 0, 0, 0); \
            accin[G][mt] = __builtin_amdgcn_mfma_f32_16x16x32_bf16(xf[mt][0], wihf[2][0], (f32x4)0.f, 0, 0, 0); \
            accr[G][mt]  = __builtin_amdgcn_mfma_f32_16x16x32_bf16(xf[mt][1], wihf[0][1], accr[G][mt], 0, 0, 0); \
            accz[G][mt]  = __builtin_amdgcn_mfma_f32_16x16x32_bf16(xf[mt][1], wihf[1][1], accz[G][mt], 0, 0, 0); \
            accin[G][mt] = __builtin_amdgcn_mfma_f32_16x16x32_bf16(xf[mt][1], wihf[2][1], accin[G][mt], 0, 0, 0); \
            if (t > 0) {                                                          \
                acchn[G][mt] = __builtin_amdgcn_mfma_f32_16x16x32_bf16(hf[mt][0], whhf[2][0], (f32x4)0.f, 0, 0, 0); \
                _Pragma("unroll")                                                 \
                for (int kc = 0; kc < 4; kc++) {                                  \
                    accr[G][mt]  = __builtin_amdgcn_mfma_f32_16x16x32_bf16(hf[mt][kc], whhf[0][kc], accr[G][mt], 0, 0, 0);  \
                    accz[G][mt]  = __builtin_amdgcn_mfma_f32_16x16x32_bf16(hf[mt][kc], whhf[1][kc], accz[G][mt], 0, 0, 0);  \
                }                                                                 \
                _Pragma("unroll")                                                 \
                for (int kc = 1; kc < 4; kc++)                                    \
                    acchn[G][mt] = __builtin_amdgcn_mfma_f32_16x16x32_bf16(hf[mt][kc], whhf[2][kc], acchn[G][mt], 0, 0, 0); \
            } else {                                                              \
                acchn[G][mt] = (f32x4)0.f;                                        \
            }                                                                     \
        }                                                                         \
        if (DO_GATE) GATE_BLOCK(PG, PG, DO_HW, HWB);                              \
        if (DO_XW) {                                                              \
            int2 pv;                                                              \
            pv.x = (int)bfpk(xh[PG].x, xh[PG].y);                                 \
            pv.y = (int)bfpk(xh[PG].z, xh[PG].w);                                 \
            *(int2*)&xB[PG][XWB][sn][sk] = pv;                                    \
        }                                                                         \
        BAR();                                                                    \
    }

    for (int t = 0; t < SEQ; t++) {
        GRU_PHASE(0, 1, (t > 0), ((t - 1) & 1), (t > 0), 1, (t & 1), xs0)
        GRU_PHASE(1, 0, 1, (t & 1), (t + 1 < SEQ), (t + 1 < SEQ), ((t + 1) & 1), xs1)
    }
#undef GRU_PHASE

    GATE_BLOCK(1, 1, 0, 0);
#undef GATE_BLOCK

#pragma unroll
    for (int g = 0; g < 2; g++)
#pragma unroll
        for (int mt = 0; mt < 2; mt++)
#pragma unroll
            for (int r = 0; r < 4; r++)
                hout[(size_t)(n0 + g * 32 + mt * 16 + q * 4 + r) * HID + ch] = hreg[g][mt][r];
}

// ---------------------------------------------------------------------------
// CSR build
// ---------------------------------------------------------------------------
__global__ void count_edges(const int* __restrict__ dst, int* __restrict__ deg, int e)
{
    int i = blockIdx.x * 256 + threadIdx.x;
    if (i < e) atomicAdd(&deg[dst[i]], 1);
}

__device__ __forceinline__ int block_scan_inc(int v)
{
    int tid = threadIdx.x, lane = tid & 63, w = tid >> 6;
#pragma unroll
    for (int off = 1; off < 64; off <<= 1) {
        int tmp = __shfl_up(v, off, 64);
        if (lane >= off) v += tmp;
    }
    __shared__ int wsum[4];
    if (lane == 63) wsum[w] = v;
    __syncthreads();
    int add = 0;
    for (int i = 0; i < w; i++) add += wsum[i];
    return v + add;
}

__global__ void scan_block_sums(const int* __restrict__ deg, int* __restrict__ bsum, int n)
{
    int i = blockIdx.x * 256 + threadIdx.x;
    int v = (i < n) ? deg[i] : 0;
#pragma unroll
    for (int off = 32; off >= 1; off >>= 1) v += __shfl_xor(v, off, 64);
    __shared__ int ws[4];
    if ((threadIdx.x & 63) == 0) ws[threadIdx.x >> 6] = v;
    __syncthreads();
    if (threadIdx.x == 0) bsum[blockIdx.x] = ws[0] + ws[1] + ws[2] + ws[3];
}

__global__ void scan_bsum(int* __restrict__ bsum, int nb)
{
    int tid = threadIdx.x;
    int v = (tid < nb) ? bsum[tid] : 0;
    v = block_scan_inc(v);
    if (tid < nb) bsum[tid] = v;
}

__global__ void scan_final(const int* __restrict__ deg, const int* __restrict__ bsum,
                           int* __restrict__ rp, int n)
{
    int i = blockIdx.x * 256 + threadIdx.x;
    int v = (i < n) ? deg[i] : 0;
    int s = block_scan_inc(v);
    int add = (blockIdx.x > 0) ? bsum[blockIdx.x - 1] : 0;
    if (i < n) rp[i + 1] = s + add;
    if (i == 0) rp[0] = 0;
}

__global__ void fill_edges(const int* __restrict__ src, const int* __restrict__ dst,
                           const int* __restrict__ rp, int* __restrict__ cur,
                           int* __restrict__ col, int e)
{
    int i = blockIdx.x * 256 + threadIdx.x;
    if (i < e) {
        int d = dst[i];
        int pos = atomicAdd(&cur[d], 1);
        col[rp[d] + pos] = src[i];
    }
}

// ---------------------------------------------------------------------------
// GAT projection + attention coefficients, fp16 MFMA rewrite.
// Block: 256 threads = 4 waves, 32 nodes. Wave w owns out-ch [32w,32w+32).
// x staged to LDS as fp16; B-frags packed from ORIGINAL [out][in] weights
// (k-contiguous, same pattern as gru) -> prep_weights/transpose deleted.
// Epilogue via fp32 ot tile: hph fp16 pack + a_src/a_dst dots (unchanged).
// fp16 inputs: ~5e-4 rel error (vs bf16 4e-3) -- negligible added absmax.
// ---------------------------------------------------------------------------
__global__ __launch_bounds__(256) void proj_attn(
    const float* __restrict__ x, const float* __restrict__ w,   // w: [128][128] row-major
    const float* __restrict__ a_src, const float* __restrict__ a_dst,
    unsigned* __restrict__ hph, float* __restrict__ as_, float* __restrict__ ad_)
{
    __shared__ __align__(16) unsigned short xt[32][136];   // fp16 bits
    __shared__ __align__(16) float ot[32][132];
    const int tid = threadIdx.x;
    const int wv = tid >> 6, lane = tid & 63;
    const int q = lane >> 4, rl = lane & 15;
    const int n0 = blockIdx.x * 32;

    // B-frags: out-ch row = 32*wv + nf*16 + rl, k contiguous
    half8 wf[2][4];
#pragma unroll
    for (int nf = 0; nf < 2; nf++)
#pragma unroll
        for (int kc = 0; kc < 4; kc++) {
            const float* p = w + (32 * wv + nf * 16 + rl) * HID + kc * 32 + q * 8;
            wf[nf][kc] = pack8h(*(const float4*)p, *(const float4*)(p + 4));
        }

    // stage x tile fp32 -> fp16: thread owns node tid>>3, 16 ch at (tid&7)*16
    {
        const int nn = tid >> 3, c0 = (tid & 7) * 16;
        const float* xp = x + (size_t)(n0 + nn) * HID + c0;
        float4 v0 = *(const float4*)(xp + 0);
        float4 v1 = *(const float4*)(xp + 4);
        float4 v2 = *(const float4*)(xp + 8);
        float4 v3 = *(const float4*)(xp + 12);
        uint4 pv;
        pv.x = hfpk(v0.x, v0.y); pv.y = hfpk(v0.z, v0.w);
        pv.z = hfpk(v1.x, v1.y); pv.w = hfpk(v1.z, v1.w);
        *(uint4*)&xt[nn][c0] = pv;
        pv.x = hfpk(v2.x, v2.y); pv.y = hfpk(v2.z, v2.w);
        pv.z = hfpk(v3.x, v3.y); pv.w = hfpk(v3.z, v3.w);
        *(uint4*)&xt[nn][c0 + 8] = pv;
    }
    __syncthreads();

    f32x4 acc[2][2];
#pragma unroll
    for (int mt = 0; mt < 2; mt++)
#pragma unroll
        for (int nf = 0; nf < 2; nf++) acc[mt][nf] = (f32x4)0.f;

#pragma unroll
    for (int kc = 0; kc < 4; kc++) {
        half8 af0 = *(const half8*)&xt[rl][kc * 32 + q * 8];
        half8 af1 = *(const half8*)&xt[16 + rl][kc * 32 + q * 8];
        acc[0][0] = __builtin_amdgcn_mfma_f32_16x16x32_f16(af0, wf[0][kc], acc[0][0], 0, 0, 0);
        acc[0][1] = __builtin_amdgcn_mfma_f32_16x16x32_f16(af0, wf[1][kc], acc[0][1], 0, 0, 0);
        acc[1][0] = __builtin_amdgcn_mfma_f32_16x16x32_f16(af1, wf[0][kc], acc[1][0], 0, 0, 0);
        acc[1][1] = __builtin_amdgcn_mfma_f32_16x16x32_f16(af1, wf[1][kc], acc[1][1], 0, 0, 0);
    }

    // D layout: node = mt*16 + q*4 + r, ch = 32*wv + nf*16 + rl
#pragma unroll
    for (int mt = 0; mt < 2; mt++)
#pragma unroll
        for (int nf = 0; nf < 2; nf++)
#pragma unroll
            for (int r = 0; r < 4; r++)
                ot[mt * 16 + q * 4 + r][32 * wv + nf * 16 + rl] = acc[mt][nf][r];
    __syncthreads();

    // hph fp16 pack from ot
    {
        const int nn = tid >> 3, c0 = (tid & 7) * 16;
        float4 v0 = *(const float4*)&ot[nn][c0];
        float4 v1 = *(const float4*)&ot[nn][c0 + 4];
        float4 v2 = *(const float4*)&ot[nn][c0 + 8];
        float4 v3 = *(const float4*)&ot[nn][c0 + 12];
        uint4 pv;
        pv.x = hfpk(v0.x, v0.y); pv.y = hfpk(v0.z, v0.w);
        pv.z = hfpk(v1.x, v1.y); pv.w = hfpk(v1.z, v1.w);
        *(uint4*)&hph[(size_t)(n0 + nn) * 64 + c0 / 2] = pv;
        pv.x = hfpk(v2.x, v2.y); pv.y = hfpk(v2.z, v2.w);
        pv.z = hfpk(v3.x, v3.y); pv.w = hfpk(v3.z, v3.w);
        *(uint4*)&hph[(size_t)(n0 + nn) * 64 + c0 / 2 + 4] = pv;
    }

    // attention dots
    if (tid < 128) {
        int node = tid >> 2, head = tid & 3;
        const float* ar = a_src + head * 32;
        const float* br = a_dst + head * 32;
        float s = 0.f, d = 0.f;
#pragma unroll
        for (int j = 0; j < 32; j += 4) {
            float4 hv = *(const float4*)&ot[node][head * 32 + j];
            float4 av = *(const float4*)&ar[j];
            float4 bv = *(const float4*)&br[j];
            s += hv.x * av.x + hv.y * av.y + hv.z * av.z + hv.w * av.w;
            d += hv.x * bv.x + hv.y * bv.y + hv.z * bv.z + hv.w * bv.w;
        }
        as_[(n0 + node) * 4 + head] = s;
        ad_[(n0 + node) * 4 + head] = d;
    }
}

// ---------------------------------------------------------------------------
// GAT aggregation, single-pass rewrite: one wave per dst node.
// Key: with lane = (head, ch-pair) layout, each lane computes its head's
// edge weight w = exp(lrelu(as+ad)) redundantly (1 trans op/edge/wave --
// free) and accumulates the denominator per-lane -> NO phase-A pass, NO
// exl LDS cache, NO cross-lane reduction, no AGG_CAP split. Halves the
// per-edge loads; kernel uses zero LDS.
// ---------------------------------------------------------------------------
template <bool CLF>
__global__ __launch_bounds__(256) void gat_agg(
    const unsigned* __restrict__ hph, const float* __restrict__ as_,
    const float* __restrict__ ad_, const int* __restrict__ rp,
    const int* __restrict__ col, const float* __restrict__ bias,
    float* __restrict__ out, const float* __restrict__ cw,
    const float* __restrict__ cb, int n_nodes)
{
    const int lane = threadIdx.x & 63;
    const int n = blockIdx.x * 4 + (threadIdx.x >> 6);
    if (n >= n_nodes) return;

    const int e0 = rp[n], e1 = rp[n + 1];
    const int head = lane >> 4;
    const float adh = ad_[n * 4 + head];

    // self-loop
    float wself = __expf(lrelu02(as_[n * 4 + head] + adh));
    float2 sv = h2f2(hph[(size_t)n * 64 + lane]);
    float den = wself;
    float acc0 = wself * sv.x;
    float acc1 = wself * sv.y;

    int e = e0;
    for (; e + 4 <= e1; e += 4) {
        int s0 = col[e], s1 = col[e + 1], s2 = col[e + 2], s3 = col[e + 3];
        float a0 = as_[s0 * 4 + head];
        float a1 = as_[s1 * 4 + head];
        float a2 = as_[s2 * 4 + head];
        float a3 = as_[s3 * 4 + head];
        unsigned u0 = hph[(size_t)s0 * 64 + lane];
        unsigned u1 = hph[(size_t)s1 * 64 + lane];
        unsigned u2 = hph[(size_t)s2 * 64 + lane];
        unsigned u3 = hph[(size_t)s3 * 64 + lane];
        float w0 = __expf(lrelu02(a0 + adh));
        float w1 = __expf(lrelu02(a1 + adh));
        float w2 = __expf(lrelu02(a2 + adh));
        float w3 = __expf(lrelu02(a3 + adh));
        float2 f0 = h2f2(u0), f1 = h2f2(u1), f2 = h2f2(u2), f3 = h2f2(u3);
        den += w0 + w1 + w2 + w3;
        acc0 = fmaf(w0, f0.x, acc0); acc1 = fmaf(w0, f0.y, acc1);
        acc0 = fmaf(w1, f1.x, acc0); acc1 = fmaf(w1, f1.y, acc1);
        acc0 = fmaf(w2, f2.x, acc0); acc1 = fmaf(w2, f2.y, acc1);
        acc0 = fmaf(w3, f3.x, acc0); acc1 = fmaf(w3, f3.y, acc1);
    }
    for (; e < e1; e++) {
        int s = col[e];
        float a = as_[s * 4 + head];
        unsigned u = hph[(size_t)s * 64 + lane];
        float w = __expf(lrelu02(a + adh));
        float2 f = h2f2(u);
        den += w;
        acc0 = fmaf(w, f.x, acc0);
        acc1 = fmaf(w, f.y, acc1);
    }

    float invh = frcp(den + 1e-16f);
    float2 b2 = *(const float2*)&bias[2 * lane];
    float o0 = eluf_(acc0 * invh + b2.x);
    float o1 = eluf_(acc1 * invh + b2.y);
    if (CLF) {
        float2 cwv = *(const float2*)&cw[2 * lane];
        float v = o0 * cwv.x + o1 * cwv.y;
#pragma unroll
        for (int off = 32; off >= 1; off >>= 1) v += __shfl_xor(v, off, 64);
        if (lane == 0) out[n] = sigmoidf_(v + cb[0]);
    } else {
        *(float2*)&out[(size_t)n * HID + 2 * lane] = make_float2(o0, o1);
    }
}

// ---------------------------------------------------------------------------
extern "C" void kernel_launch(void* const* d_in, const int* in_sizes, int n_in,
                              void* d_out, int out_size, void* d_ws, size_t ws_size,
                              hipStream_t stream)
{
    const float* x     = (const float*)d_in[0];
    const int*   ei    = (const int*)d_in[1];
    const float* w_ih  = (const float*)d_in[2];
    const float* w_hh  = (const float*)d_in[3];
    const float* b_ih  = (const float*)d_in[4];
    const float* b_hh  = (const float*)d_in[5];
    const float* g1w   = (const float*)d_in[6];
    const float* g1as  = (const float*)d_in[7];
    const float* g1ad  = (const float*)d_in[8];
    const float* g1b   = (const float*)d_in[9];
    const float* g2w   = (const float*)d_in[10];
    const float* g2as  = (const float*)d_in[11];
    const float* g2ad  = (const float*)d_in[12];
    const float* g2b   = (const float*)d_in[13];
    const float* cw    = (const float*)d_in[14];
    const float* cb    = (const float*)d_in[15];
    float* out = (float*)d_out;

    char* wsb = (char*)d_ws;
    size_t off = 0;
    auto alc = [&](size_t bytes) { size_t o = off; off += (bytes + 255) & ~(size_t)255; return o; };

    float*    bufA = (float*)(wsb + alc((size_t)NP * HID * 4));      // GRU h
    float*    bufC = (float*)(wsb + alc((size_t)NP * HID * 4));      // layer-1 out
    unsigned* hph  = (unsigned*)(wsb + alc((size_t)NP * 64 * 4));    // fp16-packed features
    float*    as_  = (float*)(wsb + alc((size_t)NP * 4 * 4));
    float*    ad_  = (float*)(wsb + alc((size_t)NP * 4 * 4));
    int*      rp   = (int*)(wsb + alc((size_t)(N_NODES + 1) * 4));
    int*      deg  = (int*)(wsb + alc((size_t)N_NODES * 4));
    int*      cur  = (int*)(wsb + alc((size_t)N_NODES * 4));
    int*      col  = (int*)(wsb + alc((size_t)NEDGE * 4));
    int*      bsum = (int*)(wsb + alc((size_t)256 * 4));

    const int* src = ei;
    const int* dst = ei + NEDGE;

    hipMemsetAsync(deg, 0, (size_t)N_NODES * 4, stream);
    hipMemsetAsync(cur, 0, (size_t)N_NODES * 4, stream);

    // CSR build (reused by both GAT layers)
    count_edges<<<NEDGE / 256, 256, 0, stream>>>(dst, deg, NEDGE);
    scan_block_sums<<<NB_SCAN, 256, 0, stream>>>(deg, bsum, N_NODES);
    scan_bsum<<<1, 256, 0, stream>>>(bsum, NB_SCAN);
    scan_final<<<NB_SCAN, 256, 0, stream>>>(deg, bsum, rp, N_NODES);
    fill_edges<<<NEDGE / 256, 256, 0, stream>>>(src, dst, rp, cur, col, NEDGE);

    // fused GRU (all 16 steps), bf16 MFMA, gate-deferred pipeline, h -> bufA
    gru_fused<<<NP / 64, 512, 0, stream>>>(x, w_ih, w_hh, b_ih, b_hh, bufA);

    // GAT layer 1: bufA -> hph/as_/ad_ (fp16 MFMA proj+attn) -> bufC (agg+elu)
    proj_attn<<<NP / 32, 256, 0, stream>>>(bufA, g1w, g1as, g1ad, hph, as_, ad_);
    gat_agg<false><<<(N_NODES + 3) / 4, 256, 0, stream>>>(hph, as_, ad_, rp, col, g1b, bufC,
                                                          nullptr, nullptr, N_NODES);

    // GAT layer 2: bufC -> hph/as_/ad_; agg fused with classifier -> out
    proj_attn<<<NP / 32, 256, 0, stream>>>(bufC, g2w, g2as, g2ad, hph, as_, ad_);
    gat_agg<true><<<(N_NODES + 3) / 4, 256, 0, stream>>>(hph, as_, ad_, rp, col, g2b, out,
                                                         cw, cb, N_NODES);
}